// Round 2
// baseline (3387.273 us; speedup 1.0000x reference)
//
#include <hip/hip_runtime.h>
#include <math.h>

#define DM 512
#define NH 8
#define HD 64
#define BB 16
#define SS 1024
#define NROWS (BB*SS)   // 16384
#define IND 16

// ---------------- input projections: history = feat@hw^T+hb, x = feat@qw^T+qb ----------------
__global__ __launch_bounds__(256) void k_input_proj(
    const float* __restrict__ feat, const float* __restrict__ hw, const float* __restrict__ hb,
    const float* __restrict__ qw, const float* __restrict__ qb,
    float* __restrict__ hist, float* __restrict__ x) {
  int row = blockIdx.x;
  __shared__ float f[IND];
  if (threadIdx.x < IND) f[threadIdx.x] = feat[(size_t)row*IND + threadIdx.x];
  __syncthreads();
  for (int c = threadIdx.x; c < DM; c += 256) {
    const float4* hw4 = (const float4*)(hw + (size_t)c*IND);
    const float4* qw4 = (const float4*)(qw + (size_t)c*IND);
    float aH = hb[c], aQ = qb[c];
    #pragma unroll
    for (int i4 = 0; i4 < 4; i4++) {
      float4 h4 = hw4[i4], q4 = qw4[i4];
      const float* fp = f + i4*4;
      aH += h4.x*fp[0] + h4.y*fp[1] + h4.z*fp[2] + h4.w*fp[3];
      aQ += q4.x*fp[0] + q4.y*fp[1] + q4.z*fp[2] + q4.w*fp[3];
    }
    hist[(size_t)row*DM + c] = aH;
    x[(size_t)row*DM + c]    = aQ;
  }
}

// ---------------- SGEMM: C = A[M,512] @ W[Ncols,512]^T + bias, various epilogues ----------------
// EPI 0: plain C0[m*N+n]
// EPI 1: head layout C0[((b*NH+h)*SS+s)*HD+d]      (N=512)
// EPI 2: dual head layout: n<512 -> C0(k), else C1(v)  (N=1024)
// EPI 3: plain + residual: C0[m*N+n] = acc + bias + resid[m*N+n]
template<int EPI>
__global__ __launch_bounds__(256) void k_sgemm(
    const float* __restrict__ A, const float* __restrict__ W,
    const float* __restrict__ bias, const float* __restrict__ resid,
    float* __restrict__ C0, float* __restrict__ C1, int N) {
  const int K = DM;
  __shared__ float As[16][68];
  __shared__ float Ws[16][68];
  int bm = blockIdx.y * 64, bn = blockIdx.x * 64;
  int tid = threadIdx.x;
  int tx = tid & 15, ty = tid >> 4;        // tx -> n, ty -> m
  int lr = tid >> 2, lk = (tid & 3) * 4;   // load indices
  float acc[4][4] = {};
  const float* Ap = A + (size_t)(bm + lr)*K + lk;
  const float* Wp = W + (size_t)(bn + lr)*K + lk;
  for (int k0 = 0; k0 < K; k0 += 16) {
    float4 a4 = *(const float4*)(Ap + k0);
    float4 w4 = *(const float4*)(Wp + k0);
    __syncthreads();
    As[lk+0][lr]=a4.x; As[lk+1][lr]=a4.y; As[lk+2][lr]=a4.z; As[lk+3][lr]=a4.w;
    Ws[lk+0][lr]=w4.x; Ws[lk+1][lr]=w4.y; Ws[lk+2][lr]=w4.z; Ws[lk+3][lr]=w4.w;
    __syncthreads();
    #pragma unroll
    for (int kk = 0; kk < 16; kk++) {
      float4 av = *(const float4*)&As[kk][ty*4];
      float4 wv = *(const float4*)&Ws[kk][tx*4];
      float am[4] = {av.x,av.y,av.z,av.w};
      float wm[4] = {wv.x,wv.y,wv.z,wv.w};
      #pragma unroll
      for (int i=0;i<4;i++)
        #pragma unroll
        for (int j=0;j<4;j++) acc[i][j] += am[i]*wm[j];
    }
  }
  #pragma unroll
  for (int i=0;i<4;i++) {
    int m = bm + ty*4 + i;
    #pragma unroll
    for (int j=0;j<4;j++) {
      int n = bn + tx*4 + j;
      float vout = acc[i][j] + bias[n];
      if (EPI == 0) {
        C0[(size_t)m*N + n] = vout;
      } else if (EPI == 1) {
        int b = m >> 10, s = m & 1023, h = n >> 6, d = n & 63;
        C0[(((size_t)(b*NH + h))*SS + s)*HD + d] = vout;
      } else if (EPI == 2) {
        int sel = n >> 9, n2 = n & 511;
        int b = m >> 10, s = m & 1023, h = n2 >> 6, d = n2 & 63;
        float* Cp = sel ? C1 : C0;
        Cp[(((size_t)(b*NH + h))*SS + s)*HD + d] = vout;
      } else {
        C0[(size_t)m*N + n] = vout + resid[(size_t)m*N + n];
      }
    }
  }
}

// ---------------- flash attention, fp32, causal; q/k/v in (B,H,S,HD) ----------------
__global__ __launch_bounds__(256) void k_attn(
    const float* __restrict__ q, const float* __restrict__ k, const float* __restrict__ v,
    float* __restrict__ ctx) {
  int qt = blockIdx.x;   // 0..15, 64-row q tile
  int bh = blockIdx.y;   // 0..127
  int b = bh >> 3, h = bh & 7;
  const float* qp = q + (size_t)bh * SS * HD;
  const float* kp = k + (size_t)bh * SS * HD;
  const float* vp = v + (size_t)bh * SS * HD;

  __shared__ float Qs[64][68];
  __shared__ float Ks[64][68];
  __shared__ float Vt[64][68];   // transposed: Vt[d][kcol]
  __shared__ float Ps[64][68];

  int tid = threadIdx.x;
  int tx = tid & 15, ty = tid >> 4;
  int lc  = (tid & 15) * 4;      // d offset for loads
  int lr0 = tid >> 4;            // base row for loads

  // load Q tile (64x64)
  #pragma unroll
  for (int u = 0; u < 4; u++) {
    int r = lr0 + 16*u;
    float4 t4 = *(const float4*)(qp + (size_t)(qt*64 + r)*HD + lc);
    *(float4*)&Qs[r][lc] = t4;
  }

  float o[4][4] = {};
  float mrun[4], lrun[4];
  #pragma unroll
  for (int i=0;i<4;i++){ mrun[i] = -1e30f; lrun[i] = 0.f; }
  const float scale = 0.125f; // 1/sqrt(64)

  for (int kt = 0; kt <= qt; kt++) {
    __syncthreads();  // prior tile's LDS reads done (also orders Q writes before first reads)
    #pragma unroll
    for (int u = 0; u < 4; u++) {
      int r = lr0 + 16*u;
      float4 k4g = *(const float4*)(kp + (size_t)(kt*64 + r)*HD + lc);
      *(float4*)&Ks[r][lc] = k4g;
      float4 v4g = *(const float4*)(vp + (size_t)(kt*64 + r)*HD + lc);
      Vt[lc+0][r] = v4g.x; Vt[lc+1][r] = v4g.y; Vt[lc+2][r] = v4g.z; Vt[lc+3][r] = v4g.w;
    }
    __syncthreads();

    // scores: rows ty*4+i, kcols tx+16*jj
    float s[4][4] = {};
    #pragma unroll
    for (int d4 = 0; d4 < 16; d4++) {
      float4 q4[4], k4[4];
      #pragma unroll
      for (int i=0;i<4;i++)  q4[i]  = *(const float4*)&Qs[ty*4+i][d4*4];
      #pragma unroll
      for (int jj=0;jj<4;jj++) k4[jj] = *(const float4*)&Ks[tx+16*jj][d4*4];
      #pragma unroll
      for (int i=0;i<4;i++)
        #pragma unroll
        for (int jj=0;jj<4;jj++)
          s[i][jj] += q4[i].x*k4[jj].x + q4[i].y*k4[jj].y + q4[i].z*k4[jj].z + q4[i].w*k4[jj].w;
    }
    bool diag = (kt == qt);
    #pragma unroll
    for (int i=0;i<4;i++) {
      int qrow = qt*64 + ty*4 + i;
      #pragma unroll
      for (int jj=0;jj<4;jj++) {
        int kcol = kt*64 + tx + 16*jj;
        float sv = s[i][jj] * scale;
        if (diag && kcol > qrow) sv = -1e30f;
        s[i][jj] = sv;
      }
    }
    // online softmax (row stats across the 16 tx lanes)
    #pragma unroll
    for (int i=0;i<4;i++) {
      float tm = fmaxf(fmaxf(s[i][0],s[i][1]), fmaxf(s[i][2],s[i][3]));
      #pragma unroll
      for (int off=1; off<16; off<<=1) tm = fmaxf(tm, __shfl_xor(tm, off));
      float mnew = fmaxf(mrun[i], tm);
      float corr = __expf(mrun[i] - mnew);
      float rs = 0.f;
      #pragma unroll
      for (int jj=0;jj<4;jj++) { float p = __expf(s[i][jj] - mnew); s[i][jj] = p; rs += p; }
      #pragma unroll
      for (int off=1; off<16; off<<=1) rs += __shfl_xor(rs, off);
      lrun[i] = lrun[i]*corr + rs;
      mrun[i] = mnew;
      #pragma unroll
      for (int j=0;j<4;j++) o[i][j] *= corr;
      #pragma unroll
      for (int jj=0;jj<4;jj++) Ps[ty*4+i][tx+16*jj] = s[i][jj];
    }
    __syncthreads();
    // PV: o[i][j] += sum_kk Ps[qrow][kk] * Vt[dcol][kk], dcol = tx+16*j
    #pragma unroll
    for (int k4i = 0; k4i < 16; k4i++) {
      float4 p4[4], v4[4];
      #pragma unroll
      for (int i=0;i<4;i++) p4[i] = *(const float4*)&Ps[ty*4+i][k4i*4];
      #pragma unroll
      for (int j=0;j<4;j++) v4[j] = *(const float4*)&Vt[tx+16*j][k4i*4];
      #pragma unroll
      for (int i=0;i<4;i++)
        #pragma unroll
        for (int j=0;j<4;j++)
          o[i][j] += p4[i].x*v4[j].x + p4[i].y*v4[j].y + p4[i].z*v4[j].z + p4[i].w*v4[j].w;
    }
  }
  #pragma unroll
  for (int i=0;i<4;i++) {
    int qrow = qt*64 + ty*4 + i;
    float inv = 1.f / lrun[i];
    #pragma unroll
    for (int j=0;j<4;j++) {
      int dcol = tx + 16*j;
      ctx[((size_t)(b*SS + qrow))*DM + h*HD + dcol] = o[i][j] * inv;
    }
  }
}

// ---------------- LayerNorm over last dim 512: x = LN(t)*g + b ----------------
__global__ __launch_bounds__(256) void k_ln(
    const float* __restrict__ t, const float* __restrict__ g,
    const float* __restrict__ b, float* __restrict__ x) {
  int row = blockIdx.x*4 + (threadIdx.x>>6);
  int lane = threadIdx.x & 63;
  const float* tr = t + (size_t)row*DM;
  float vals[8]; float s1=0.f, s2=0.f;
  #pragma unroll
  for (int u=0;u<8;u++){ float vv = tr[lane + 64*u]; vals[u]=vv; s1+=vv; s2+=vv*vv; }
  #pragma unroll
  for (int off=1; off<64; off<<=1){ s1 += __shfl_xor(s1,off); s2 += __shfl_xor(s2,off); }
  float mu  = s1 * (1.0f/DM);
  float var = s2 * (1.0f/DM) - mu*mu;
  float inv = rsqrtf(var + 1e-5f);
  float* xr = x + (size_t)row*DM;
  #pragma unroll
  for (int u=0;u<8;u++){ int c = lane+64*u; xr[c] = (vals[u]-mu)*inv*g[c] + b[c]; }
}

// ---------------- head: out = 1.5*tanh(x@w^T + b) ----------------
__global__ __launch_bounds__(256) void k_head(
    const float* __restrict__ x, const float* __restrict__ w,
    const float* __restrict__ b, float* __restrict__ out) {
  int row = blockIdx.x*4 + (threadIdx.x>>6);
  int lane = threadIdx.x & 63;
  const float* xr = x + (size_t)row*DM;
  float acc = 0.f;
  #pragma unroll
  for (int u=0;u<8;u++) acc += xr[lane+64*u]*w[lane+64*u];
  #pragma unroll
  for (int off=1; off<64; off<<=1) acc += __shfl_xor(acc,off);
  if (lane == 0) out[row] = 1.5f * tanhf(acc + b[0]);
}

extern "C" void kernel_launch(void* const* d_in, const int* in_sizes, int n_in,
                              void* d_out, int out_size, void* d_ws, size_t ws_size,
                              hipStream_t stream) {
  (void)in_sizes; (void)n_in; (void)out_size; (void)ws_size;
  const float* feat      = (const float*)d_in[0];
  const float* hist_w    = (const float*)d_in[1];
  const float* hist_b    = (const float*)d_in[2];
  const float* query_w   = (const float*)d_in[3];
  const float* query_b   = (const float*)d_in[4];
  const float* in_proj_w = (const float*)d_in[5];
  const float* in_proj_b = (const float*)d_in[6];
  const float* attn_w    = (const float*)d_in[7];
  const float* attn_b    = (const float*)d_in[8];
  const float* ln_g      = (const float*)d_in[9];
  const float* ln_b      = (const float*)d_in[10];
  const float* out_w     = (const float*)d_in[11];
  const float* out_b     = (const float*)d_in[12];
  float* out = (float*)d_out;

  float* ws = (float*)d_ws;
  const size_t P = (size_t)NROWS * DM;   // 8.39M floats per buffer
  float* hist = ws;
  float* x    = ws + P;
  float* qb_  = ws + 2*P;   // q (head layout); reused as pre-LN tmp
  float* kb_  = ws + 3*P;
  float* vb_  = ws + 4*P;
  float* cb_  = ws + 5*P;   // attention context (B,S,D)

  k_input_proj<<<NROWS, 256, 0, stream>>>(feat, hist_w, hist_b, query_w, query_b, hist, x);

  for (int l = 0; l < 2; l++) {
    const float* wq  = in_proj_w + (size_t)l*3*DM*DM;
    const float* wkv = wq + (size_t)DM*DM;
    const float* bq  = in_proj_b + (size_t)l*3*DM;
    const float* bkv = bq + DM;
    dim3 gq (DM/64,   NROWS/64);
    dim3 gkv(2*DM/64, NROWS/64);
    k_sgemm<1><<<gq,  256, 0, stream>>>(x,    wq,  bq,  nullptr, qb_, nullptr, DM);
    k_sgemm<2><<<gkv, 256, 0, stream>>>(hist, wkv, bkv, nullptr, kb_, vb_,   2*DM);
    dim3 ga(SS/64, BB*NH);
    k_attn<<<ga, 256, 0, stream>>>(qb_, kb_, vb_, cb_);
    const float* wo = attn_w + (size_t)l*DM*DM;
    const float* bo = attn_b + (size_t)l*DM;
    k_sgemm<3><<<gq, 256, 0, stream>>>(cb_, wo, bo, x, qb_, nullptr, DM);
    k_ln<<<NROWS/4, 256, 0, stream>>>(qb_, ln_g + (size_t)l*DM, ln_b + (size_t)l*DM, x);
  }
  k_head<<<NROWS/4, 256, 0, stream>>>(x, out_w, out_b, out);
}

// Round 4
// 1383.340 us; speedup vs baseline: 2.4486x; 2.4486x over previous
//
#include <hip/hip_runtime.h>
#include <math.h>

#define DM 512
#define NH 8
#define HD 64
#define BB 16
#define SS 1024
#define NROWS (BB*SS)   // 16384
#define IND 16

typedef unsigned short u16;
typedef __attribute__((ext_vector_type(8))) short bf16x8;
typedef __attribute__((ext_vector_type(4))) float f32x4;

// round-to-nearest-even f32 -> bf16 (no NaN handling; inputs are finite)
static __device__ __forceinline__ u16 f2bf(float f) {
  union { float f; unsigned int u; } v; v.f = f;
  unsigned int r = v.u + 0x7FFFu + ((v.u >> 16) & 1u);
  return (u16)(r >> 16);
}

// ---------------- input projections ----------------
__global__ __launch_bounds__(256) void k_input_proj(
    const float* __restrict__ feat, const float* __restrict__ hw, const float* __restrict__ hb,
    const float* __restrict__ qw, const float* __restrict__ qb,
    float* __restrict__ hist, float* __restrict__ x) {
  int row = blockIdx.x;
  __shared__ float f[IND];
  if (threadIdx.x < IND) f[threadIdx.x] = feat[(size_t)row*IND + threadIdx.x];
  __syncthreads();
  for (int c = threadIdx.x; c < DM; c += 256) {
    const float4* hw4 = (const float4*)(hw + (size_t)c*IND);
    const float4* qw4 = (const float4*)(qw + (size_t)c*IND);
    float aH = hb[c], aQ = qb[c];
    #pragma unroll
    for (int i4 = 0; i4 < 4; i4++) {
      float4 h4 = hw4[i4], q4 = qw4[i4];
      const float* fp = f + i4*4;
      aH += h4.x*fp[0] + h4.y*fp[1] + h4.z*fp[2] + h4.w*fp[3];
      aQ += q4.x*fp[0] + q4.y*fp[1] + q4.z*fp[2] + q4.w*fp[3];
    }
    hist[(size_t)row*DM + c] = aH;
    x[(size_t)row*DM + c]    = aQ;
  }
}

// ---------------- SGEMM: C = A[M,512] @ W[Ncols,512]^T + bias ----------------
// EPI 1: Q bf16 head layout (b,h,s,d), scaled by 0.125
// EPI 2: n<512 -> K bf16 (b,h,s,d); n>=512 -> V bf16 TRANSPOSED (b,h,d,s)
// EPI 3: fp32 plain + residual
template<int EPI>
__global__ __launch_bounds__(256) void k_sgemm(
    const float* __restrict__ A, const float* __restrict__ W,
    const float* __restrict__ bias, const float* __restrict__ resid,
    float* __restrict__ C0f, u16* __restrict__ C0h, u16* __restrict__ C1h, int N) {
  const int K = DM;
  __shared__ float As[16][68];
  __shared__ float Ws[16][68];
  int bm = blockIdx.y * 64, bn = blockIdx.x * 64;
  int tid = threadIdx.x;
  int tx = tid & 15, ty = tid >> 4;        // tx -> n, ty -> m
  int lr = tid >> 2, lk = (tid & 3) * 4;   // load indices
  float acc[4][4] = {};
  const float* Ap = A + (size_t)(bm + lr)*K + lk;
  const float* Wp = W + (size_t)(bn + lr)*K + lk;
  for (int k0 = 0; k0 < K; k0 += 16) {
    float4 a4 = *(const float4*)(Ap + k0);
    float4 w4 = *(const float4*)(Wp + k0);
    __syncthreads();
    As[lk+0][lr]=a4.x; As[lk+1][lr]=a4.y; As[lk+2][lr]=a4.z; As[lk+3][lr]=a4.w;
    Ws[lk+0][lr]=w4.x; Ws[lk+1][lr]=w4.y; Ws[lk+2][lr]=w4.z; Ws[lk+3][lr]=w4.w;
    __syncthreads();
    #pragma unroll
    for (int kk = 0; kk < 16; kk++) {
      float4 av = *(const float4*)&As[kk][ty*4];
      float4 wv = *(const float4*)&Ws[kk][tx*4];
      float am[4] = {av.x,av.y,av.z,av.w};
      float wm[4] = {wv.x,wv.y,wv.z,wv.w};
      #pragma unroll
      for (int i=0;i<4;i++)
        #pragma unroll
        for (int j=0;j<4;j++) acc[i][j] += am[i]*wm[j];
    }
  }
  float fb[4];
  #pragma unroll
  for (int j=0;j<4;j++) fb[j] = bias[bn + tx*4 + j];
  int b0i = bm >> 10;                // batch (uniform in block: bm aligned 64)
  int s0  = (bm & 1023) + ty*4;      // seq base for this thread's rows

  if (EPI == 1 || (EPI == 2 && bn < 512)) {
    int h = (bn >> 6) & 7;
    size_t base = (size_t)(b0i*NH + h) * SS;
    const float sc = (EPI == 1) ? 0.125f : 1.0f;
    #pragma unroll
    for (int i=0;i<4;i++) {
      ushort4 pk;
      pk.x = f2bf((acc[i][0] + fb[0]) * sc);
      pk.y = f2bf((acc[i][1] + fb[1]) * sc);
      pk.z = f2bf((acc[i][2] + fb[2]) * sc);
      pk.w = f2bf((acc[i][3] + fb[3]) * sc);
      *(ushort4*)&C0h[(base + s0 + i)*HD + tx*4] = pk;
    }
  } else if (EPI == 2) {
    int h = (bn - 512) >> 6;
    size_t base = (size_t)(b0i*NH + h) * HD;
    #pragma unroll
    for (int j=0;j<4;j++) {
      int d = tx*4 + j;
      ushort4 pk;
      pk.x = f2bf(acc[0][j] + fb[j]);
      pk.y = f2bf(acc[1][j] + fb[j]);
      pk.z = f2bf(acc[2][j] + fb[j]);
      pk.w = f2bf(acc[3][j] + fb[j]);
      *(ushort4*)&C1h[(base + d)*SS + s0] = pk;
    }
  } else {
    #pragma unroll
    for (int i=0;i<4;i++) {
      int m = bm + ty*4 + i;
      #pragma unroll
      for (int j=0;j<4;j++) {
        int n = bn + tx*4 + j;
        C0f[(size_t)m*DM + n] = acc[i][j] + fb[j] + resid[(size_t)m*DM + n];
      }
    }
  }
}

// ---------------- flash attention, bf16 MFMA, causal ----------------
// Q,K: bf16 (b,h,s,d); Vt: bf16 (b,h,d,s). Q pre-scaled by 1/sqrt(64).
// Block: 256 thr = 4 waves; 64 q-rows/block (16 per wave). K-tile = 64.
// LDS tiles row-major 64x64 bf16 with 16B-unit XOR swizzle: unit ^= (row&7).
__global__ __launch_bounds__(256) void k_attn_mfma(
    const u16* __restrict__ Q, const u16* __restrict__ K,
    const u16* __restrict__ Vt, float* __restrict__ ctx) {
  int qt = blockIdx.x;          // 0..15
  int bh = blockIdx.y;          // 0..127
  int b = bh >> 3, h = bh & 7;
  int tid = threadIdx.x;
  int w = tid >> 6, lane = tid & 63;
  int lq = lane & 15, g = lane >> 4;   // frag row / k-group
  int l7 = lq & 7;

  __shared__ u16 Ks[4096];   // [64 kk][64 d] swizzled
  __shared__ u16 Vs[4096];   // [64 d][64 kk] swizzled
  __shared__ u16 Ps[4096];   // per-wave 16x64 strips, swizzled

  // Q fragments (A): row m=lq of wave strip, k = g*8 + i (+32)
  const u16* qbase = Q + ((size_t)bh*SS + qt*64 + w*16 + lq)*HD;
  bf16x8 qa0 = *(const bf16x8*)(qbase + g*8);
  bf16x8 qa1 = *(const bf16x8*)(qbase + g*8 + 32);

  f32x4 o[4];
  #pragma unroll
  for (int nb=0;nb<4;nb++) o[nb] = (f32x4){0.f,0.f,0.f,0.f};
  float mrun[4], lrun[4];
  #pragma unroll
  for (int r=0;r<4;r++) { mrun[r] = -1e30f; lrun[r] = 0.f; }

  // staging indices: thread -> row sr (0..63), 16B-unit su (0..3) and su+4
  int sr = tid >> 2, su = tid & 3;
  int kw0 = sr*64 + ((su       ^ (sr&7)) << 3);
  int kw1 = sr*64 + (((su + 4) ^ (sr&7)) << 3);
  const u16* vgb = Vt + ((size_t)bh*HD + sr)*SS;   // row sr = d
  int pbase = w*1024;

  for (int kt = 0; kt <= qt; kt++) {
    __syncthreads();
    { // stage K and Vt tiles (global bf16 -> LDS swizzled)
      const u16* kg = K + ((size_t)bh*SS + kt*64 + sr)*HD;
      bf16x8 kv0 = *(const bf16x8*)(kg + su*8);
      bf16x8 kv1 = *(const bf16x8*)(kg + su*8 + 32);
      const u16* vg = vgb + kt*64;
      bf16x8 vv0 = *(const bf16x8*)(vg + su*8);
      bf16x8 vv1 = *(const bf16x8*)(vg + su*8 + 32);
      *(bf16x8*)&Ks[kw0] = kv0; *(bf16x8*)&Ks[kw1] = kv1;
      *(bf16x8*)&Vs[kw0] = vv0; *(bf16x8*)&Vs[kw1] = vv1;
    }
    __syncthreads();

    // ---- S = Q K^T  (D[m=q][n=kk]) ----
    f32x4 s[4];
    #pragma unroll
    for (int nb=0;nb<4;nb++) s[nb] = (f32x4){0.f,0.f,0.f,0.f};
    #pragma unroll
    for (int ks=0; ks<2; ks++) {
      bf16x8 aq = ks ? qa1 : qa0;
      #pragma unroll
      for (int nb=0;nb<4;nb++) {
        bf16x8 kb = *(const bf16x8*)&Ks[(lq + 16*nb)*64 + (((g + 4*ks) ^ l7) << 3)];
        s[nb] = __builtin_amdgcn_mfma_f32_16x16x32_bf16(aq, kb, s[nb], 0, 0, 0);
      }
    }

    // ---- mask + online softmax (per q-row r; row = w*16+g*4+r) ----
    bool diag = (kt == qt);
    #pragma unroll
    for (int r=0;r<4;r++) {
      int qrow = w*16 + g*4 + r;          // tile-local q row
      if (diag) {
        #pragma unroll
        for (int nb=0;nb<4;nb++)
          if (lq + 16*nb > qrow) s[nb][r] = -1e30f;
      }
      float rm = fmaxf(fmaxf(s[0][r], s[1][r]), fmaxf(s[2][r], s[3][r]));
      #pragma unroll
      for (int off=1; off<16; off<<=1) rm = fmaxf(rm, __shfl_xor(rm, off));
      float mnew = fmaxf(mrun[r], rm);
      float corr = __expf(mrun[r] - mnew);
      float psum = 0.f;
      #pragma unroll
      for (int nb=0;nb<4;nb++) {
        float p = __expf(s[nb][r] - mnew);
        psum += p;
        int mrow = g*4 + r;
        Ps[pbase + mrow*64 + ((((lq>>3) + 2*nb) ^ (mrow&7)) << 3) + l7] = f2bf(p);
      }
      #pragma unroll
      for (int off=1; off<16; off<<=1) psum += __shfl_xor(psum, off);
      lrun[r] = lrun[r]*corr + psum;
      mrun[r] = mnew;
      #pragma unroll
      for (int nb=0;nb<4;nb++) o[nb][r] *= corr;
    }

    // ---- O += P V  (A = P rows lq; B = Vs rows d=lq+16nb) ----
    #pragma unroll
    for (int ks=0; ks<2; ks++) {
      bf16x8 pa = *(const bf16x8*)&Ps[pbase + lq*64 + (((g + 4*ks) ^ l7) << 3)];
      #pragma unroll
      for (int nb=0;nb<4;nb++) {
        bf16x8 vb = *(const bf16x8*)&Vs[(lq + 16*nb)*64 + (((g + 4*ks) ^ l7) << 3)];
        o[nb] = __builtin_amdgcn_mfma_f32_16x16x32_bf16(pa, vb, o[nb], 0, 0, 0);
      }
    }
  }

  // ---- epilogue: ctx (b, s, D) fp32 ----
  #pragma unroll
  for (int r=0;r<4;r++) {
    float inv = 1.f / lrun[r];
    int qrow = qt*64 + w*16 + g*4 + r;
    float* cp = ctx + ((size_t)b*SS + qrow)*DM + h*HD;
    #pragma unroll
    for (int nb=0;nb<4;nb++) cp[lq + 16*nb] = o[nb][r] * inv;
  }
}

// ---------------- LayerNorm over last dim 512 ----------------
__global__ __launch_bounds__(256) void k_ln(
    const float* __restrict__ t, const float* __restrict__ g,
    const float* __restrict__ b, float* __restrict__ x) {
  int row = blockIdx.x*4 + (threadIdx.x>>6);
  int lane = threadIdx.x & 63;
  const float* tr = t + (size_t)row*DM;
  float vals[8]; float s1=0.f, s2=0.f;
  #pragma unroll
  for (int u=0;u<8;u++){ float vv = tr[lane + 64*u]; vals[u]=vv; s1+=vv; s2+=vv*vv; }
  #pragma unroll
  for (int off=1; off<64; off<<=1){ s1 += __shfl_xor(s1,off); s2 += __shfl_xor(s2,off); }
  float mu  = s1 * (1.0f/DM);
  float var = s2 * (1.0f/DM) - mu*mu;
  float inv = rsqrtf(var + 1e-5f);
  float* xr = x + (size_t)row*DM;
  #pragma unroll
  for (int u=0;u<8;u++){ int c = lane+64*u; xr[c] = (vals[u]-mu)*inv*g[c] + b[c]; }
}

// ---------------- head: out = 1.5*tanh(x@w^T + b) ----------------
__global__ __launch_bounds__(256) void k_head(
    const float* __restrict__ x, const float* __restrict__ w,
    const float* __restrict__ b, float* __restrict__ out) {
  int row = blockIdx.x*4 + (threadIdx.x>>6);
  int lane = threadIdx.x & 63;
  const float* xr = x + (size_t)row*DM;
  float acc = 0.f;
  #pragma unroll
  for (int u=0;u<8;u++) acc += xr[lane+64*u]*w[lane+64*u];
  #pragma unroll
  for (int off=1; off<64; off<<=1) acc += __shfl_xor(acc,off);
  if (lane == 0) out[row] = 1.5f * tanhf(acc + b[0]);
}

extern "C" void kernel_launch(void* const* d_in, const int* in_sizes, int n_in,
                              void* d_out, int out_size, void* d_ws, size_t ws_size,
                              hipStream_t stream) {
  (void)in_sizes; (void)n_in; (void)out_size; (void)ws_size;
  const float* feat      = (const float*)d_in[0];
  const float* hist_w    = (const float*)d_in[1];
  const float* hist_b    = (const float*)d_in[2];
  const float* query_w   = (const float*)d_in[3];
  const float* query_b   = (const float*)d_in[4];
  const float* in_proj_w = (const float*)d_in[5];
  const float* in_proj_b = (const float*)d_in[6];
  const float* attn_w    = (const float*)d_in[7];
  const float* attn_b    = (const float*)d_in[8];
  const float* ln_g      = (const float*)d_in[9];
  const float* ln_b      = (const float*)d_in[10];
  const float* out_w     = (const float*)d_in[11];
  const float* out_b     = (const float*)d_in[12];
  float* out = (float*)d_out;

  float* ws = (float*)d_ws;
  const size_t P = (size_t)NROWS * DM;   // 8.39M elems
  float* hist = ws;            // fp32
  float* x    = ws + P;        // fp32
  float* cb   = ws + 2*P;      // fp32 attention context (B,S,D)
  float* tmp  = ws + 3*P;      // fp32 pre-LN
  u16* qbf = (u16*)(ws + 4*P); // bf16 Q (b,h,s,d), prescaled
  u16* kbf = qbf + P;          // bf16 K (b,h,s,d)
  u16* vtb = kbf + P;          // bf16 V^T (b,h,d,s)

  k_input_proj<<<NROWS, 256, 0, stream>>>(feat, hist_w, hist_b, query_w, query_b, hist, x);

  for (int l = 0; l < 2; l++) {
    const float* wq  = in_proj_w + (size_t)l*3*DM*DM;
    const float* wkv = wq + (size_t)DM*DM;
    const float* bq  = in_proj_b + (size_t)l*3*DM;
    const float* bkv = bq + DM;
    dim3 gq (DM/64,   NROWS/64);
    dim3 gkv(2*DM/64, NROWS/64);
    k_sgemm<1><<<gq,  256, 0, stream>>>(x,    wq,  bq,  nullptr, nullptr, qbf, nullptr, DM);
    k_sgemm<2><<<gkv, 256, 0, stream>>>(hist, wkv, bkv, nullptr, nullptr, kbf, vtb, 2*DM);
    dim3 ga(SS/64, BB*NH);
    k_attn_mfma<<<ga, 256, 0, stream>>>(qbf, kbf, vtb, cb);
    const float* wo = attn_w + (size_t)l*DM*DM;
    const float* bo = attn_b + (size_t)l*DM;
    k_sgemm<3><<<gq, 256, 0, stream>>>(cb, wo, bo, x, tmp, nullptr, nullptr, DM);
    k_ln<<<NROWS/4, 256, 0, stream>>>(tmp, ln_g + (size_t)l*DM, ln_b + (size_t)l*DM, x);
  }
  k_head<<<NROWS/4, 256, 0, stream>>>(x, out_w, out_b, out);
}

// Round 6
// 612.004 us; speedup vs baseline: 5.5347x; 2.2603x over previous
//
#include <hip/hip_runtime.h>
#include <math.h>

#define DM 512
#define NH 8
#define HD 64
#define BB 16
#define SS 1024
#define NROWS (BB*SS)   // 16384
#define IND 16
#define KD 512

typedef unsigned short u16;
typedef __attribute__((ext_vector_type(8))) short bf16x8;
typedef __attribute__((ext_vector_type(4))) float f32x4;

// round-to-nearest-even f32 -> bf16 (finite inputs)
static __device__ __forceinline__ u16 f2bf(float f) {
  union { float f; unsigned int u; } v; v.f = f;
  unsigned int r = v.u + 0x7FFFu + ((v.u >> 16) & 1u);
  return (u16)(r >> 16);
}

// ---------------- weight f32 -> bf16 (vectorized) ----------------
__global__ __launch_bounds__(256) void k_f2bf_v(const float* __restrict__ in,
                                                u16* __restrict__ out, int n4) {
  int i = blockIdx.x * 256 + threadIdx.x;
  if (i < n4) {
    float4 v = ((const float4*)in)[i];
    ushort4 p;
    p.x = f2bf(v.x); p.y = f2bf(v.y); p.z = f2bf(v.z); p.w = f2bf(v.w);
    ((ushort4*)out)[i] = p;
  }
}

// ---------------- input projections: hist(bf16), x(f32 + bf16) ----------------
__global__ __launch_bounds__(256) void k_input_proj(
    const float* __restrict__ feat, const float* __restrict__ hw, const float* __restrict__ hb,
    const float* __restrict__ qw, const float* __restrict__ qb,
    u16* __restrict__ histb, float* __restrict__ x, u16* __restrict__ xb) {
  int row = blockIdx.x;
  __shared__ float f[IND];
  if (threadIdx.x < IND) f[threadIdx.x] = feat[(size_t)row*IND + threadIdx.x];
  __syncthreads();
  for (int c = threadIdx.x; c < DM; c += 256) {
    const float4* hw4 = (const float4*)(hw + (size_t)c*IND);
    const float4* qw4 = (const float4*)(qw + (size_t)c*IND);
    float aH = hb[c], aQ = qb[c];
    #pragma unroll
    for (int i4 = 0; i4 < 4; i4++) {
      float4 h4 = hw4[i4], q4 = qw4[i4];
      const float* fp = f + i4*4;
      aH += h4.x*fp[0] + h4.y*fp[1] + h4.z*fp[2] + h4.w*fp[3];
      aQ += q4.x*fp[0] + q4.y*fp[1] + q4.z*fp[2] + q4.w*fp[3];
    }
    histb[(size_t)row*DM + c] = f2bf(aH);
    x[(size_t)row*DM + c]     = aQ;
    xb[(size_t)row*DM + c]    = f2bf(aQ);
  }
}

// ---------------- bf16 MFMA GEMM: C = A[M,512] @ W[N,512]^T + bias ----------------
// Block 256 thr = 4 waves (2x2), tile 128x128, per-wave 64x64 (4x4 frags 16x16), BK=64.
// LDS row-major [128][64] bf16, 16B-unit XOR swizzle: unit ^= (row&7).
// EPI 1: Q bf16 (b,h,s,d) *0.125 | EPI 2: bn<512 -> K bf16 (b,h,s,d); else V^T bf16 (b,h,d,s)
// EPI 3: fp32 in-place: Cf[m,n] = acc + bias + Cf[m,n] (resid==Cf)
template<int EPI>
__global__ __launch_bounds__(256) void k_bgemm(
    const u16* __restrict__ A, const u16* __restrict__ Wb,
    const float* __restrict__ bias,
    float* __restrict__ Cf, u16* __restrict__ C0h, u16* __restrict__ C1h) {
  __shared__ u16 As[128*64];
  __shared__ u16 Bs[128*64];
  int bm = blockIdx.y * 128, bn = blockIdx.x * 128;
  int tid = threadIdx.x;
  int w = tid >> 6, lane = tid & 63;
  int wm = (w >> 1) * 64, wn = (w & 1) * 64;
  int lq = lane & 15, g = lane >> 4, l7 = lq & 7;

  // staging: row = tid>>1 (0..127), 4 contiguous 8-elem units from (tid&1)*4
  int srow = tid >> 1;
  int su0 = (tid & 1) * 4;
  const u16* Ag = A  + (size_t)(bm + srow)*KD + su0*8;
  const u16* Bg = Wb + (size_t)(bn + srow)*KD + su0*8;
  int sw[4];
  #pragma unroll
  for (int i=0;i<4;i++) sw[i] = srow*64 + (((su0+i) ^ (srow&7)) << 3);

  f32x4 acc[4][4];
  #pragma unroll
  for (int mf=0;mf<4;mf++)
    #pragma unroll
    for (int nf=0;nf<4;nf++) acc[mf][nf] = (f32x4){0.f,0.f,0.f,0.f};

  #pragma unroll 1
  for (int k0 = 0; k0 < KD; k0 += 64) {
    bf16x8 ar[4], br[4];
    #pragma unroll
    for (int i=0;i<4;i++) {
      ar[i] = *(const bf16x8*)(Ag + k0 + i*8);
      br[i] = *(const bf16x8*)(Bg + k0 + i*8);
    }
    __syncthreads();
    #pragma unroll
    for (int i=0;i<4;i++) { *(bf16x8*)&As[sw[i]] = ar[i]; *(bf16x8*)&Bs[sw[i]] = br[i]; }
    __syncthreads();
    #pragma unroll
    for (int ks=0; ks<2; ks++) {
      int un = ((g + 4*ks) ^ l7) << 3;
      bf16x8 af[4], bfr[4];
      #pragma unroll
      for (int mf=0;mf<4;mf++) af[mf]  = *(const bf16x8*)&As[(wm + mf*16 + lq)*64 + un];
      #pragma unroll
      for (int nf=0;nf<4;nf++) bfr[nf] = *(const bf16x8*)&Bs[(wn + nf*16 + lq)*64 + un];
      #pragma unroll
      for (int mf=0;mf<4;mf++)
        #pragma unroll
        for (int nf=0;nf<4;nf++)
          acc[mf][nf] = __builtin_amdgcn_mfma_f32_16x16x32_bf16(af[mf], bfr[nf], acc[mf][nf], 0, 0, 0);
    }
  }

  float fb[4];
  #pragma unroll
  for (int nf=0;nf<4;nf++) fb[nf] = bias[bn + wn + nf*16 + lq];
  int m0 = bm + wm + g*4;
  int n0 = bn + wn + lq;

  if (EPI == 1 || (EPI == 2 && bn < 512)) {
    const float sc = (EPI == 1) ? 0.125f : 1.0f;
    #pragma unroll
    for (int mf=0;mf<4;mf++) {
      int mb = m0 + mf*16;
      int b = mb >> 10, s = mb & 1023;
      #pragma unroll
      for (int nf=0;nf<4;nf++) {
        int n = n0 + nf*16;
        int h = (n >> 6) & 7, d = n & 63;
        u16* dst = C0h + (((size_t)(b*NH + h))*SS + s)*HD + d;
        #pragma unroll
        for (int r=0;r<4;r++) dst[r*HD] = f2bf((acc[mf][nf][r] + fb[nf]) * sc);
      }
    }
  } else if (EPI == 2) {
    #pragma unroll
    for (int mf=0;mf<4;mf++) {
      int mb = m0 + mf*16;
      int b = mb >> 10, s = mb & 1023;
      #pragma unroll
      for (int nf=0;nf<4;nf++) {
        int n = n0 + nf*16 - 512;
        int h = n >> 6, d = n & 63;
        ushort4 pk;
        pk.x = f2bf(acc[mf][nf][0] + fb[nf]);
        pk.y = f2bf(acc[mf][nf][1] + fb[nf]);
        pk.z = f2bf(acc[mf][nf][2] + fb[nf]);
        pk.w = f2bf(acc[mf][nf][3] + fb[nf]);
        *(ushort4*)&C1h[(((size_t)(b*NH + h))*HD + d)*SS + s] = pk;
      }
    }
  } else {
    #pragma unroll
    for (int mf=0;mf<4;mf++) {
      #pragma unroll
      for (int r=0;r<4;r++) {
        int m = m0 + mf*16 + r;
        #pragma unroll
        for (int nf=0;nf<4;nf++) {
          int n = n0 + nf*16;
          Cf[(size_t)m*DM + n] = acc[mf][nf][r] + fb[nf] + Cf[(size_t)m*DM + n];
        }
      }
    }
  }
}

// ---------------- flash attention, bf16 MFMA, causal; ctx out bf16 ----------------
__global__ __launch_bounds__(256) void k_attn_mfma(
    const u16* __restrict__ Q, const u16* __restrict__ K,
    const u16* __restrict__ Vt, u16* __restrict__ ctxb) {
  int qt = blockIdx.x;          // 0..15
  int bh = blockIdx.y;          // 0..127
  int b = bh >> 3, h = bh & 7;
  int tid = threadIdx.x;
  int w = tid >> 6, lane = tid & 63;
  int lq = lane & 15, g = lane >> 4;
  int l7 = lq & 7;

  __shared__ u16 Ks[4096];
  __shared__ u16 Vs[4096];
  __shared__ u16 Ps[4096];

  const u16* qbase = Q + ((size_t)bh*SS + qt*64 + w*16 + lq)*HD;
  bf16x8 qa0 = *(const bf16x8*)(qbase + g*8);
  bf16x8 qa1 = *(const bf16x8*)(qbase + g*8 + 32);

  f32x4 o[4];
  #pragma unroll
  for (int nb=0;nb<4;nb++) o[nb] = (f32x4){0.f,0.f,0.f,0.f};
  float mrun[4], lrun[4];
  #pragma unroll
  for (int r=0;r<4;r++) { mrun[r] = -1e30f; lrun[r] = 0.f; }

  int sr = tid >> 2, su = tid & 3;
  int kw0 = sr*64 + ((su       ^ (sr&7)) << 3);
  int kw1 = sr*64 + (((su + 4) ^ (sr&7)) << 3);
  const u16* vgb = Vt + ((size_t)bh*HD + sr)*SS;
  int pbase = w*1024;

  for (int kt = 0; kt <= qt; kt++) {
    __syncthreads();
    {
      const u16* kg = K + ((size_t)bh*SS + kt*64 + sr)*HD;
      bf16x8 kv0 = *(const bf16x8*)(kg + su*8);
      bf16x8 kv1 = *(const bf16x8*)(kg + su*8 + 32);
      const u16* vg = vgb + kt*64;
      bf16x8 vv0 = *(const bf16x8*)(vg + su*8);
      bf16x8 vv1 = *(const bf16x8*)(vg + su*8 + 32);
      *(bf16x8*)&Ks[kw0] = kv0; *(bf16x8*)&Ks[kw1] = kv1;
      *(bf16x8*)&Vs[kw0] = vv0; *(bf16x8*)&Vs[kw1] = vv1;
    }
    __syncthreads();

    f32x4 s[4];
    #pragma unroll
    for (int nb=0;nb<4;nb++) s[nb] = (f32x4){0.f,0.f,0.f,0.f};
    #pragma unroll
    for (int ks=0; ks<2; ks++) {
      bf16x8 aq = ks ? qa1 : qa0;
      #pragma unroll
      for (int nb=0;nb<4;nb++) {
        bf16x8 kb = *(const bf16x8*)&Ks[(lq + 16*nb)*64 + (((g + 4*ks) ^ l7) << 3)];
        s[nb] = __builtin_amdgcn_mfma_f32_16x16x32_bf16(aq, kb, s[nb], 0, 0, 0);
      }
    }

    bool diag = (kt == qt);
    #pragma unroll
    for (int r=0;r<4;r++) {
      int qrow = w*16 + g*4 + r;
      if (diag) {
        #pragma unroll
        for (int nb=0;nb<4;nb++)
          if (lq + 16*nb > qrow) s[nb][r] = -1e30f;
      }
      float rm = fmaxf(fmaxf(s[0][r], s[1][r]), fmaxf(s[2][r], s[3][r]));
      #pragma unroll
      for (int off=1; off<16; off<<=1) rm = fmaxf(rm, __shfl_xor(rm, off));
      float mnew = fmaxf(mrun[r], rm);
      float corr = __expf(mrun[r] - mnew);
      float psum = 0.f;
      #pragma unroll
      for (int nb=0;nb<4;nb++) {
        float p = __expf(s[nb][r] - mnew);
        psum += p;
        int mrow = g*4 + r;
        Ps[pbase + mrow*64 + ((((lq>>3) + 2*nb) ^ (mrow&7)) << 3) + l7] = f2bf(p);
      }
      #pragma unroll
      for (int off=1; off<16; off<<=1) psum += __shfl_xor(psum, off);
      lrun[r] = lrun[r]*corr + psum;
      mrun[r] = mnew;
      #pragma unroll
      for (int nb=0;nb<4;nb++) o[nb][r] *= corr;
    }

    #pragma unroll
    for (int ks=0; ks<2; ks++) {
      bf16x8 pa = *(const bf16x8*)&Ps[pbase + lq*64 + (((g + 4*ks) ^ l7) << 3)];
      #pragma unroll
      for (int nb=0;nb<4;nb++) {
        bf16x8 vb = *(const bf16x8*)&Vs[(lq + 16*nb)*64 + (((g + 4*ks) ^ l7) << 3)];
        o[nb] = __builtin_amdgcn_mfma_f32_16x16x32_bf16(pa, vb, o[nb], 0, 0, 0);
      }
    }
  }

  #pragma unroll
  for (int r=0;r<4;r++) {
    float inv = 1.f / lrun[r];
    int qrow = qt*64 + w*16 + g*4 + r;
    u16* cp = ctxb + ((size_t)b*SS + qrow)*DM + h*HD;
    #pragma unroll
    for (int nb=0;nb<4;nb++) cp[lq + 16*nb] = f2bf(o[nb][r] * inv);
  }
}

// ---------------- LayerNorm in-place on x, dual write (f32 + bf16) ----------------
__global__ __launch_bounds__(256) void k_ln(
    float* __restrict__ x, const float* __restrict__ g,
    const float* __restrict__ b, u16* __restrict__ xb) {
  int row = blockIdx.x*4 + (threadIdx.x>>6);
  int lane = threadIdx.x & 63;
  float* xr = x + (size_t)row*DM;
  float vals[8]; float s1=0.f, s2=0.f;
  #pragma unroll
  for (int u=0;u<8;u++){ float vv = xr[lane + 64*u]; vals[u]=vv; s1+=vv; s2+=vv*vv; }
  #pragma unroll
  for (int off=1; off<64; off<<=1){ s1 += __shfl_xor(s1,off); s2 += __shfl_xor(s2,off); }
  float mu  = s1 * (1.0f/DM);
  float var = s2 * (1.0f/DM) - mu*mu;
  float inv = rsqrtf(var + 1e-5f);
  u16* xbr = xb + (size_t)row*DM;
  #pragma unroll
  for (int u=0;u<8;u++){
    int c = lane+64*u;
    float vv = (vals[u]-mu)*inv*g[c] + b[c];
    xr[c] = vv;
    xbr[c] = f2bf(vv);
  }
}

// ---------------- head: out = 1.5*tanh(x@w^T + b) ----------------
__global__ __launch_bounds__(256) void k_head(
    const float* __restrict__ x, const float* __restrict__ w,
    const float* __restrict__ b, float* __restrict__ out) {
  int row = blockIdx.x*4 + (threadIdx.x>>6);
  int lane = threadIdx.x & 63;
  const float* xr = x + (size_t)row*DM;
  float acc = 0.f;
  #pragma unroll
  for (int u=0;u<8;u++) acc += xr[lane+64*u]*w[lane+64*u];
  #pragma unroll
  for (int off=1; off<64; off<<=1) acc += __shfl_xor(acc,off);
  if (lane == 0) out[row] = 1.5f * tanhf(acc + b[0]);
}

extern "C" void kernel_launch(void* const* d_in, const int* in_sizes, int n_in,
                              void* d_out, int out_size, void* d_ws, size_t ws_size,
                              hipStream_t stream) {
  (void)in_sizes; (void)n_in; (void)out_size; (void)ws_size;
  const float* feat      = (const float*)d_in[0];
  const float* hist_w    = (const float*)d_in[1];
  const float* hist_b    = (const float*)d_in[2];
  const float* query_w   = (const float*)d_in[3];
  const float* query_b   = (const float*)d_in[4];
  const float* in_proj_w = (const float*)d_in[5];
  const float* in_proj_b = (const float*)d_in[6];
  const float* attn_w    = (const float*)d_in[7];
  const float* attn_b    = (const float*)d_in[8];
  const float* ln_g      = (const float*)d_in[9];
  const float* ln_b      = (const float*)d_in[10];
  const float* out_w     = (const float*)d_in[11];
  const float* out_b     = (const float*)d_in[12];
  float* out = (float*)d_out;

  float* ws = (float*)d_ws;
  const size_t P = (size_t)NROWS * DM;   // 8.39M elems
  float* x    = ws;                      // fp32 residual stream
  u16* xb     = (u16*)(ws + P);          // bf16 x
  u16* histb  = xb + P;                  // bf16 history (both layers)
  u16* ctxb   = histb + P;               // bf16 attention context
  u16* qbf    = ctxb + P;                // bf16 Q (b,h,s,d) prescaled
  u16* kbf    = qbf + P;                 // bf16 K (b,h,s,d)
  u16* vtb    = kbf + P;                 // bf16 V^T (b,h,d,s)
  u16* wipb   = vtb + P;                 // bf16 in_proj_w (2*1536*512)
  u16* wob    = wipb + (size_t)2*3*DM*DM;// bf16 attn_out_w (2*512*512)

  {
    int n4i = 2*3*DM*DM/4, n4o = 2*DM*DM/4;
    k_f2bf_v<<<(n4i+255)/256, 256, 0, stream>>>(in_proj_w, wipb, n4i);
    k_f2bf_v<<<(n4o+255)/256, 256, 0, stream>>>(attn_w, wob, n4o);
  }
  k_input_proj<<<NROWS, 256, 0, stream>>>(feat, hist_w, hist_b, query_w, query_b, histb, x, xb);

  for (int l = 0; l < 2; l++) {
    const u16* wq  = wipb + (size_t)l*3*DM*DM;
    const u16* wkv = wq + (size_t)DM*DM;
    const float* bq  = in_proj_b + (size_t)l*3*DM;
    const float* bkv = bq + DM;
    k_bgemm<1><<<dim3(4, 128), 256, 0, stream>>>(xb,    wq,  bq,  nullptr, qbf, nullptr);
    k_bgemm<2><<<dim3(8, 128), 256, 0, stream>>>(histb, wkv, bkv, nullptr, kbf, vtb);
    dim3 ga(SS/64, BB*NH);
    k_attn_mfma<<<ga, 256, 0, stream>>>(qbf, kbf, vtb, ctxb);
    const u16* wo = wob + (size_t)l*DM*DM;
    const float* bo = attn_b + (size_t)l*DM;
    k_bgemm<3><<<dim3(4, 128), 256, 0, stream>>>(ctxb, wo, bo, x, nullptr, nullptr);
    k_ln<<<NROWS/4, 256, 0, stream>>>(x, ln_g + (size_t)l*DM, ln_b + (size_t)l*DM, xb);
  }
  k_head<<<NROWS/4, 256, 0, stream>>>(x, out_w, out_b, out);
}

// Round 8
// 522.745 us; speedup vs baseline: 6.4798x; 1.1708x over previous
//
#include <hip/hip_runtime.h>
#include <math.h>

#define DM 512
#define NH 8
#define HD 64
#define BB 16
#define SS 1024
#define NROWS (BB*SS)   // 16384
#define IND 16
#define KD 512

typedef unsigned short u16;
typedef __attribute__((ext_vector_type(8))) short bf16x8;
typedef __attribute__((ext_vector_type(4))) float f32x4;

// round-to-nearest-even f32 -> bf16 (finite inputs)
static __device__ __forceinline__ u16 f2bf(float f) {
  union { float f; unsigned int u; } v; v.f = f;
  unsigned int r = v.u + 0x7FFFu + ((v.u >> 16) & 1u);
  return (u16)(r >> 16);
}

// ---------------- weight f32 -> bf16 (vectorized) ----------------
__global__ __launch_bounds__(256) void k_f2bf_v(const float* __restrict__ in,
                                                u16* __restrict__ out, int n4) {
  int i = blockIdx.x * 256 + threadIdx.x;
  if (i < n4) {
    float4 v = ((const float4*)in)[i];
    ushort4 p;
    p.x = f2bf(v.x); p.y = f2bf(v.y); p.z = f2bf(v.z); p.w = f2bf(v.w);
    ((ushort4*)out)[i] = p;
  }
}

// ---------------- input projections: hist(bf16), x(f32 + bf16) ----------------
__global__ __launch_bounds__(256) void k_input_proj(
    const float* __restrict__ feat, const float* __restrict__ hw, const float* __restrict__ hb,
    const float* __restrict__ qw, const float* __restrict__ qb,
    u16* __restrict__ histb, float* __restrict__ x, u16* __restrict__ xb) {
  int row = blockIdx.x;
  __shared__ float f[IND];
  if (threadIdx.x < IND) f[threadIdx.x] = feat[(size_t)row*IND + threadIdx.x];
  __syncthreads();
  for (int c = threadIdx.x; c < DM; c += 256) {
    const float4* hw4 = (const float4*)(hw + (size_t)c*IND);
    const float4* qw4 = (const float4*)(qw + (size_t)c*IND);
    float aH = hb[c], aQ = qb[c];
    #pragma unroll
    for (int i4 = 0; i4 < 4; i4++) {
      float4 h4 = hw4[i4], q4 = qw4[i4];
      const float* fp = f + i4*4;
      aH += h4.x*fp[0] + h4.y*fp[1] + h4.z*fp[2] + h4.w*fp[3];
      aQ += q4.x*fp[0] + q4.y*fp[1] + q4.z*fp[2] + q4.w*fp[3];
    }
    histb[(size_t)row*DM + c] = f2bf(aH);
    x[(size_t)row*DM + c]     = aQ;
    xb[(size_t)row*DM + c]    = f2bf(aQ);
  }
}

// ---------------- bf16 MFMA GEMM: C = A[M,512] @ W[N,512]^T + bias ----------------
template<int EPI>
__global__ __launch_bounds__(256) void k_bgemm(
    const u16* __restrict__ A, const u16* __restrict__ Wb,
    const float* __restrict__ bias,
    float* __restrict__ Cf, u16* __restrict__ C0h, u16* __restrict__ C1h) {
  __shared__ u16 As[128*64];
  __shared__ u16 Bs[128*64];
  int bm = blockIdx.y * 128, bn = blockIdx.x * 128;
  int tid = threadIdx.x;
  int w = tid >> 6, lane = tid & 63;
  int wm = (w >> 1) * 64, wn = (w & 1) * 64;
  int lq = lane & 15, g = lane >> 4, l7 = lq & 7;

  int srow = tid >> 1;
  int su0 = (tid & 1) * 4;
  const u16* Ag = A  + (size_t)(bm + srow)*KD + su0*8;
  const u16* Bg = Wb + (size_t)(bn + srow)*KD + su0*8;
  int sw[4];
  #pragma unroll
  for (int i=0;i<4;i++) sw[i] = srow*64 + (((su0+i) ^ (srow&7)) << 3);

  f32x4 acc[4][4];
  #pragma unroll
  for (int mf=0;mf<4;mf++)
    #pragma unroll
    for (int nf=0;nf<4;nf++) acc[mf][nf] = (f32x4){0.f,0.f,0.f,0.f};

  #pragma unroll 1
  for (int k0 = 0; k0 < KD; k0 += 64) {
    bf16x8 ar[4], br[4];
    #pragma unroll
    for (int i=0;i<4;i++) {
      ar[i] = *(const bf16x8*)(Ag + k0 + i*8);
      br[i] = *(const bf16x8*)(Bg + k0 + i*8);
    }
    __syncthreads();
    #pragma unroll
    for (int i=0;i<4;i++) { *(bf16x8*)&As[sw[i]] = ar[i]; *(bf16x8*)&Bs[sw[i]] = br[i]; }
    __syncthreads();
    #pragma unroll
    for (int ks=0; ks<2; ks++) {
      int un = ((g + 4*ks) ^ l7) << 3;
      bf16x8 af[4], bfr[4];
      #pragma unroll
      for (int mf=0;mf<4;mf++) af[mf]  = *(const bf16x8*)&As[(wm + mf*16 + lq)*64 + un];
      #pragma unroll
      for (int nf=0;nf<4;nf++) bfr[nf] = *(const bf16x8*)&Bs[(wn + nf*16 + lq)*64 + un];
      #pragma unroll
      for (int mf=0;mf<4;mf++)
        #pragma unroll
        for (int nf=0;nf<4;nf++)
          acc[mf][nf] = __builtin_amdgcn_mfma_f32_16x16x32_bf16(af[mf], bfr[nf], acc[mf][nf], 0, 0, 0);
    }
  }

  float fb[4];
  #pragma unroll
  for (int nf=0;nf<4;nf++) fb[nf] = bias[bn + wn + nf*16 + lq];
  int m0 = bm + wm + g*4;
  int n0 = bn + wn + lq;

  if (EPI == 1 || (EPI == 2 && bn < 512)) {
    const float sc = (EPI == 1) ? 0.125f : 1.0f;
    #pragma unroll
    for (int mf=0;mf<4;mf++) {
      int mb = m0 + mf*16;
      int b = mb >> 10, s = mb & 1023;
      #pragma unroll
      for (int nf=0;nf<4;nf++) {
        int n = n0 + nf*16;
        int h = (n >> 6) & 7, d = n & 63;
        u16* dst = C0h + (((size_t)(b*NH + h))*SS + s)*HD + d;
        #pragma unroll
        for (int r=0;r<4;r++) dst[r*HD] = f2bf((acc[mf][nf][r] + fb[nf]) * sc);
      }
    }
  } else if (EPI == 2) {
    #pragma unroll
    for (int mf=0;mf<4;mf++) {
      int mb = m0 + mf*16;
      int b = mb >> 10, s = mb & 1023;
      #pragma unroll
      for (int nf=0;nf<4;nf++) {
        int n = n0 + nf*16 - 512;
        int h = n >> 6, d = n & 63;
        ushort4 pk;
        pk.x = f2bf(acc[mf][nf][0] + fb[nf]);
        pk.y = f2bf(acc[mf][nf][1] + fb[nf]);
        pk.z = f2bf(acc[mf][nf][2] + fb[nf]);
        pk.w = f2bf(acc[mf][nf][3] + fb[nf]);
        *(ushort4*)&C1h[(((size_t)(b*NH + h))*HD + d)*SS + s] = pk;
      }
    }
  } else {
    #pragma unroll
    for (int mf=0;mf<4;mf++) {
      #pragma unroll
      for (int r=0;r<4;r++) {
        int m = m0 + mf*16 + r;
        #pragma unroll
        for (int nf=0;nf<4;nf++) {
          int n = n0 + nf*16;
          Cf[(size_t)m*DM + n] = acc[mf][nf][r] + fb[nf] + Cf[(size_t)m*DM + n];
        }
      }
    }
  }
}

// ---------------- flash attention, bf16 MFMA, causal; 512 thr, 128 q-rows/block ----------------
// Q,K: bf16 (b,h,s,d); Vt: bf16 (b,h,d,s). Q pre-scaled by 1/sqrt(64).
// 8 waves x 16 q-rows; K-tile 64; K/V prefetched to regs (latency hidden under compute).
__global__ __launch_bounds__(512) void k_attn_mfma(
    const u16* __restrict__ Q, const u16* __restrict__ K,
    const u16* __restrict__ Vt, u16* __restrict__ ctxb) {
  int qt2 = blockIdx.x;         // 0..7 (128-row q tile)
  int bh = blockIdx.y;          // 0..127
  int b = bh >> 3, h = bh & 7;
  int tid = threadIdx.x;
  int w = tid >> 6, lane = tid & 63;
  int lq = lane & 15, g = lane >> 4;
  int l7 = lq & 7;

  __shared__ u16 Ks[4096];   // [64 kk][64 d], 16B-unit XOR swizzle (row&7)
  __shared__ u16 Vs[4096];   // [64 d][64 kk], same swizzle
  __shared__ u16 Ps[8192];   // 8 waves x 16x64 strip, same swizzle

  // Q fragments: row = w*16+lq within 128-row tile
  const u16* qbase = Q + ((size_t)bh*SS + qt2*128 + w*16 + lq)*HD;
  bf16x8 qa0 = *(const bf16x8*)(qbase + g*8);
  bf16x8 qa1 = *(const bf16x8*)(qbase + g*8 + 32);

  f32x4 o[4];
  #pragma unroll
  for (int nb=0;nb<4;nb++) o[nb] = (f32x4){0.f,0.f,0.f,0.f};
  float mrun[4], lrun[4];
  #pragma unroll
  for (int r=0;r<4;r++) { mrun[r] = -1e30f; lrun[r] = 0.f; }

  // staging: thread -> row sr (0..63), 16B-unit su (0..7); one K + one V 16B load each
  int sr = tid >> 3, su = tid & 7;
  int kw = sr*64 + ((su ^ (sr&7)) << 3);
  const u16* kgb = K + ((size_t)bh*SS + sr)*HD + su*8;   // + kt*64*HD
  const u16* vgb = Vt + ((size_t)bh*HD + sr)*SS + su*8;  // + kt*64
  int pbase = w*1024;
  int last = 2*qt2 + 1;

  bf16x8 kreg = *(const bf16x8*)kgb;
  bf16x8 vreg = *(const bf16x8*)vgb;

  for (int kt = 0; kt <= last; kt++) {
    __syncthreads();   // prior iter's LDS reads complete
    *(bf16x8*)&Ks[kw] = kreg;
    *(bf16x8*)&Vs[kw] = vreg;
    __syncthreads();
    if (kt < last) {   // prefetch next tile; latency hides under compute below
      kreg = *(const bf16x8*)(kgb + (size_t)(kt+1)*64*HD);
      vreg = *(const bf16x8*)(vgb + (kt+1)*64);
    }
    // wave-uniform skip: tile entirely above this wave's rows
    if (kt*64 > qt2*128 + w*16 + 15) continue;

    // ---- S = Q K^T ----
    f32x4 s[4];
    #pragma unroll
    for (int nb=0;nb<4;nb++) s[nb] = (f32x4){0.f,0.f,0.f,0.f};
    #pragma unroll
    for (int ks=0; ks<2; ks++) {
      bf16x8 aq = ks ? qa1 : qa0;
      #pragma unroll
      for (int nb=0;nb<4;nb++) {
        bf16x8 kb = *(const bf16x8*)&Ks[(lq + 16*nb)*64 + (((g + 4*ks) ^ l7) << 3)];
        s[nb] = __builtin_amdgcn_mfma_f32_16x16x32_bf16(aq, kb, s[nb], 0, 0, 0);
      }
    }

    // ---- mask + online softmax ----
    bool diag = (kt*64 + 63 > qt2*128 + w*16);   // wave-uniform
    #pragma unroll
    for (int r=0;r<4;r++) {
      int qrow = qt2*128 + w*16 + g*4 + r;
      if (diag) {
        #pragma unroll
        for (int nb=0;nb<4;nb++)
          if (kt*64 + lq + 16*nb > qrow) s[nb][r] = -1e30f;
      }
      float rm = fmaxf(fmaxf(s[0][r], s[1][r]), fmaxf(s[2][r], s[3][r]));
      #pragma unroll
      for (int off=1; off<16; off<<=1) rm = fmaxf(rm, __shfl_xor(rm, off));
      float mnew = fmaxf(mrun[r], rm);
      float corr = __expf(mrun[r] - mnew);
      float psum = 0.f;
      int mrow = g*4 + r;
      #pragma unroll
      for (int nb=0;nb<4;nb++) {
        float p = __expf(s[nb][r] - mnew);
        psum += p;
        Ps[pbase + mrow*64 + ((((lq>>3) + 2*nb) ^ (mrow&7)) << 3) + l7] = f2bf(p);
      }
      #pragma unroll
      for (int off=1; off<16; off<<=1) psum += __shfl_xor(psum, off);
      lrun[r] = lrun[r]*corr + psum;
      mrun[r] = mnew;
      #pragma unroll
      for (int nb=0;nb<4;nb++) o[nb][r] *= corr;
    }

    // ---- O += P V ----
    #pragma unroll
    for (int ks=0; ks<2; ks++) {
      bf16x8 pa = *(const bf16x8*)&Ps[pbase + lq*64 + (((g + 4*ks) ^ l7) << 3)];
      #pragma unroll
      for (int nb=0;nb<4;nb++) {
        bf16x8 vb = *(const bf16x8*)&Vs[(lq + 16*nb)*64 + (((g + 4*ks) ^ l7) << 3)];
        o[nb] = __builtin_amdgcn_mfma_f32_16x16x32_bf16(pa, vb, o[nb], 0, 0, 0);
      }
    }
  }

  // ---- epilogue: ctx bf16 (b, s, D) ----
  #pragma unroll
  for (int r=0;r<4;r++) {
    float inv = 1.f / lrun[r];
    int qrow = qt2*128 + w*16 + g*4 + r;
    u16* cp = ctxb + ((size_t)b*SS + qrow)*DM + h*HD;
    #pragma unroll
    for (int nb=0;nb<4;nb++) cp[lq + 16*nb] = f2bf(o[nb][r] * inv);
  }
}

// ---------------- LayerNorm in-place on x, dual write (f32 + bf16) ----------------
__global__ __launch_bounds__(256) void k_ln(
    float* __restrict__ x, const float* __restrict__ g,
    const float* __restrict__ b, u16* __restrict__ xb) {
  int row = blockIdx.x*4 + (threadIdx.x>>6);
  int lane = threadIdx.x & 63;
  float* xr = x + (size_t)row*DM;
  float vals[8]; float s1=0.f, s2=0.f;
  #pragma unroll
  for (int u=0;u<8;u++){ float vv = xr[lane + 64*u]; vals[u]=vv; s1+=vv; s2+=vv*vv; }
  #pragma unroll
  for (int off=1; off<64; off<<=1){ s1 += __shfl_xor(s1,off); s2 += __shfl_xor(s2,off); }
  float mu  = s1 * (1.0f/DM);
  float var = s2 * (1.0f/DM) - mu*mu;
  float inv = rsqrtf(var + 1e-5f);
  u16* xbr = xb + (size_t)row*DM;
  #pragma unroll
  for (int u=0;u<8;u++){
    int c = lane+64*u;
    float vv = (vals[u]-mu)*inv*g[c] + b[c];
    xr[c] = vv;
    xbr[c] = f2bf(vv);
  }
}

// ---------------- head: out = 1.5*tanh(x@w^T + b) ----------------
__global__ __launch_bounds__(256) void k_head(
    const float* __restrict__ x, const float* __restrict__ w,
    const float* __restrict__ b, float* __restrict__ out) {
  int row = blockIdx.x*4 + (threadIdx.x>>6);
  int lane = threadIdx.x & 63;
  const float* xr = x + (size_t)row*DM;
  float acc = 0.f;
  #pragma unroll
  for (int u=0;u<8;u++) acc += xr[lane+64*u]*w[lane+64*u];
  #pragma unroll
  for (int off=1; off<64; off<<=1) acc += __shfl_xor(acc,off);
  if (lane == 0) out[row] = 1.5f * tanhf(acc + b[0]);
}

extern "C" void kernel_launch(void* const* d_in, const int* in_sizes, int n_in,
                              void* d_out, int out_size, void* d_ws, size_t ws_size,
                              hipStream_t stream) {
  (void)in_sizes; (void)n_in; (void)out_size; (void)ws_size;
  const float* feat      = (const float*)d_in[0];
  const float* hist_w    = (const float*)d_in[1];
  const float* hist_b    = (const float*)d_in[2];
  const float* query_w   = (const float*)d_in[3];
  const float* query_b   = (const float*)d_in[4];
  const float* in_proj_w = (const float*)d_in[5];
  const float* in_proj_b = (const float*)d_in[6];
  const float* attn_w    = (const float*)d_in[7];
  const float* attn_b    = (const float*)d_in[8];
  const float* ln_g      = (const float*)d_in[9];
  const float* ln_b      = (const float*)d_in[10];
  const float* out_w     = (const float*)d_in[11];
  const float* out_b     = (const float*)d_in[12];
  float* out = (float*)d_out;

  float* ws = (float*)d_ws;
  const size_t P = (size_t)NROWS * DM;   // 8.39M elems
  float* x    = ws;                      // fp32 residual stream
  u16* xb     = (u16*)(ws + P);          // bf16 x
  u16* histb  = xb + P;                  // bf16 history (both layers)
  u16* ctxb   = histb + P;               // bf16 attention context
  u16* qbf    = ctxb + P;                // bf16 Q (b,h,s,d) prescaled
  u16* kbf    = qbf + P;                 // bf16 K (b,h,s,d)
  u16* vtb    = kbf + P;                 // bf16 V^T (b,h,d,s)
  u16* wipb   = vtb + P;                 // bf16 in_proj_w (2*1536*512)
  u16* wob    = wipb + (size_t)2*3*DM*DM;// bf16 attn_out_w (2*512*512)

  {
    int n4i = 2*3*DM*DM/4, n4o = 2*DM*DM/4;
    k_f2bf_v<<<(n4i+255)/256, 256, 0, stream>>>(in_proj_w, wipb, n4i);
    k_f2bf_v<<<(n4o+255)/256, 256, 0, stream>>>(attn_w, wob, n4o);
  }
  k_input_proj<<<NROWS, 256, 0, stream>>>(feat, hist_w, hist_b, query_w, query_b, histb, x, xb);

  for (int l = 0; l < 2; l++) {
    const u16* wq  = wipb + (size_t)l*3*DM*DM;
    const u16* wkv = wq + (size_t)DM*DM;
    const float* bq  = in_proj_b + (size_t)l*3*DM;
    const float* bkv = bq + DM;
    k_bgemm<1><<<dim3(4, 128), 256, 0, stream>>>(xb,    wq,  bq,  nullptr, qbf, nullptr);
    k_bgemm<2><<<dim3(8, 128), 256, 0, stream>>>(histb, wkv, bkv, nullptr, kbf, vtb);
    dim3 ga(8, BB*NH);
    k_attn_mfma<<<ga, 512, 0, stream>>>(qbf, kbf, vtb, ctxb);
    const u16* wo = wob + (size_t)l*DM*DM;
    const float* bo = attn_b + (size_t)l*DM;
    k_bgemm<3><<<dim3(4, 128), 256, 0, stream>>>(ctxb, wo, bo, x, nullptr, nullptr);
    k_ln<<<NROWS/4, 256, 0, stream>>>(x, ln_g + (size_t)l*DM, ln_b + (size_t)l*DM, xb);
  }
  k_head<<<NROWS/4, 256, 0, stream>>>(x, out_w, out_b, out);
}

// Round 9
// 451.867 us; speedup vs baseline: 7.4962x; 1.1569x over previous
//
#include <hip/hip_runtime.h>
#include <math.h>

#define DM 512
#define NH 8
#define HD 64
#define BB 16
#define SS 1024
#define NROWS (BB*SS)   // 16384
#define IND 16
#define KD 512

typedef unsigned short u16;
typedef __attribute__((ext_vector_type(8))) short bf16x8;
typedef __attribute__((ext_vector_type(4))) float f32x4;

// round-to-nearest-even f32 -> bf16 (finite inputs)
static __device__ __forceinline__ u16 f2bf(float f) {
  union { float f; unsigned int u; } v; v.f = f;
  unsigned int r = v.u + 0x7FFFu + ((v.u >> 16) & 1u);
  return (u16)(r >> 16);
}

// ---------------- weight f32 -> bf16 (vectorized) ----------------
__global__ __launch_bounds__(256) void k_f2bf_v(const float* __restrict__ in,
                                                u16* __restrict__ out, int n4) {
  int i = blockIdx.x * 256 + threadIdx.x;
  if (i < n4) {
    float4 v = ((const float4*)in)[i];
    ushort4 p;
    p.x = f2bf(v.x); p.y = f2bf(v.y); p.z = f2bf(v.z); p.w = f2bf(v.w);
    ((ushort4*)out)[i] = p;
  }
}

// ---------------- input projections: hist(bf16), x(f32 + bf16) ----------------
__global__ __launch_bounds__(256) void k_input_proj(
    const float* __restrict__ feat, const float* __restrict__ hw, const float* __restrict__ hb,
    const float* __restrict__ qw, const float* __restrict__ qb,
    u16* __restrict__ histb, float* __restrict__ x, u16* __restrict__ xb) {
  int row = blockIdx.x;
  __shared__ float f[IND];
  if (threadIdx.x < IND) f[threadIdx.x] = feat[(size_t)row*IND + threadIdx.x];
  __syncthreads();
  for (int c = threadIdx.x; c < DM; c += 256) {
    const float4* hw4 = (const float4*)(hw + (size_t)c*IND);
    const float4* qw4 = (const float4*)(qw + (size_t)c*IND);
    float aH = hb[c], aQ = qb[c];
    #pragma unroll
    for (int i4 = 0; i4 < 4; i4++) {
      float4 h4 = hw4[i4], q4 = qw4[i4];
      const float* fp = f + i4*4;
      aH += h4.x*fp[0] + h4.y*fp[1] + h4.z*fp[2] + h4.w*fp[3];
      aQ += q4.x*fp[0] + q4.y*fp[1] + q4.z*fp[2] + q4.w*fp[3];
    }
    histb[(size_t)row*DM + c] = f2bf(aH);
    x[(size_t)row*DM + c]     = aQ;
    xb[(size_t)row*DM + c]    = f2bf(aQ);
  }
}

// ---------------- bf16 MFMA GEMM: C = A[M,512] @ W[N,512]^T + bias ----------------
template<int EPI>
__global__ __launch_bounds__(256) void k_bgemm(
    const u16* __restrict__ A, const u16* __restrict__ Wb,
    const float* __restrict__ bias,
    float* __restrict__ Cf, u16* __restrict__ C0h, u16* __restrict__ C1h) {
  __shared__ u16 As[128*64];
  __shared__ u16 Bs[128*64];
  int bm = blockIdx.y * 128, bn = blockIdx.x * 128;
  int tid = threadIdx.x;
  int w = tid >> 6, lane = tid & 63;
  int wm = (w >> 1) * 64, wn = (w & 1) * 64;
  int lq = lane & 15, g = lane >> 4, l7 = lq & 7;

  int srow = tid >> 1;
  int su0 = (tid & 1) * 4;
  const u16* Ag = A  + (size_t)(bm + srow)*KD + su0*8;
  const u16* Bg = Wb + (size_t)(bn + srow)*KD + su0*8;
  int sw[4];
  #pragma unroll
  for (int i=0;i<4;i++) sw[i] = srow*64 + (((su0+i) ^ (srow&7)) << 3);

  f32x4 acc[4][4];
  #pragma unroll
  for (int mf=0;mf<4;mf++)
    #pragma unroll
    for (int nf=0;nf<4;nf++) acc[mf][nf] = (f32x4){0.f,0.f,0.f,0.f};

  #pragma unroll 1
  for (int k0 = 0; k0 < KD; k0 += 64) {
    bf16x8 ar[4], br[4];
    #pragma unroll
    for (int i=0;i<4;i++) {
      ar[i] = *(const bf16x8*)(Ag + k0 + i*8);
      br[i] = *(const bf16x8*)(Bg + k0 + i*8);
    }
    __syncthreads();
    #pragma unroll
    for (int i=0;i<4;i++) { *(bf16x8*)&As[sw[i]] = ar[i]; *(bf16x8*)&Bs[sw[i]] = br[i]; }
    __syncthreads();
    #pragma unroll
    for (int ks=0; ks<2; ks++) {
      int un = ((g + 4*ks) ^ l7) << 3;
      bf16x8 af[4], bfr[4];
      #pragma unroll
      for (int mf=0;mf<4;mf++) af[mf]  = *(const bf16x8*)&As[(wm + mf*16 + lq)*64 + un];
      #pragma unroll
      for (int nf=0;nf<4;nf++) bfr[nf] = *(const bf16x8*)&Bs[(wn + nf*16 + lq)*64 + un];
      #pragma unroll
      for (int mf=0;mf<4;mf++)
        #pragma unroll
        for (int nf=0;nf<4;nf++)
          acc[mf][nf] = __builtin_amdgcn_mfma_f32_16x16x32_bf16(af[mf], bfr[nf], acc[mf][nf], 0, 0, 0);
    }
  }

  float fb[4];
  #pragma unroll
  for (int nf=0;nf<4;nf++) fb[nf] = bias[bn + wn + nf*16 + lq];
  int m0 = bm + wm + g*4;
  int n0 = bn + wn + lq;

  if (EPI == 1 || (EPI == 2 && bn < 512)) {
    const float sc = (EPI == 1) ? 0.125f : 1.0f;
    #pragma unroll
    for (int mf=0;mf<4;mf++) {
      int mb = m0 + mf*16;
      int b = mb >> 10, s = mb & 1023;
      #pragma unroll
      for (int nf=0;nf<4;nf++) {
        int n = n0 + nf*16;
        int h = (n >> 6) & 7, d = n & 63;
        u16* dst = C0h + (((size_t)(b*NH + h))*SS + s)*HD + d;
        #pragma unroll
        for (int r=0;r<4;r++) dst[r*HD] = f2bf((acc[mf][nf][r] + fb[nf]) * sc);
      }
    }
  } else if (EPI == 2) {
    #pragma unroll
    for (int mf=0;mf<4;mf++) {
      int mb = m0 + mf*16;
      int b = mb >> 10, s = mb & 1023;
      #pragma unroll
      for (int nf=0;nf<4;nf++) {
        int n = n0 + nf*16 - 512;
        int h = n >> 6, d = n & 63;
        ushort4 pk;
        pk.x = f2bf(acc[mf][nf][0] + fb[nf]);
        pk.y = f2bf(acc[mf][nf][1] + fb[nf]);
        pk.z = f2bf(acc[mf][nf][2] + fb[nf]);
        pk.w = f2bf(acc[mf][nf][3] + fb[nf]);
        *(ushort4*)&C1h[(((size_t)(b*NH + h))*HD + d)*SS + s] = pk;
      }
    }
  } else {
    #pragma unroll
    for (int mf=0;mf<4;mf++) {
      #pragma unroll
      for (int r=0;r<4;r++) {
        int m = m0 + mf*16 + r;
        #pragma unroll
        for (int nf=0;nf<4;nf++) {
          int n = n0 + nf*16;
          Cf[(size_t)m*DM + n] = acc[mf][nf][r] + fb[nf] + Cf[(size_t)m*DM + n];
        }
      }
    }
  }
}

// ---------------- flash attention, bf16 MFMA, causal; 512 thr, paired q-tiles ----------------
// Q,K: bf16 (b,h,s,d); Vt: bf16 (b,h,d,s). Q pre-scaled by 1/sqrt(64).
// blockIdx.x = i (0..3): processes 128-row q-tile i then q-tile 7-i.
// Work per block = (2i+2) + (16-2i) = 18 K-tile iterations — UNIFORM (no causal tail).
__global__ __launch_bounds__(512) void k_attn_mfma(
    const u16* __restrict__ Q, const u16* __restrict__ K,
    const u16* __restrict__ Vt, u16* __restrict__ ctxb) {
  int ip = blockIdx.x;          // 0..3 pair index
  int bh = blockIdx.y;          // 0..127
  int b = bh >> 3, h = bh & 7;
  int tid = threadIdx.x;
  int w = tid >> 6, lane = tid & 63;
  int lq = lane & 15, g = lane >> 4;
  int l7 = lq & 7;

  __shared__ u16 Ks[4096];   // [64 kk][64 d], 16B-unit XOR swizzle (row&7)
  __shared__ u16 Vs[4096];   // [64 d][64 kk], same swizzle
  __shared__ u16 Ps[8192];   // 8 waves x 16x64 strip, same swizzle

  // staging: thread -> row sr (0..63), 16B-unit su (0..7); one K + one V 16B load each
  int sr = tid >> 3, su = tid & 7;
  int kw = sr*64 + ((su ^ (sr&7)) << 3);
  const u16* kgb = K + ((size_t)bh*SS + sr)*HD + su*8;   // + kt*64*HD
  const u16* vgb = Vt + ((size_t)bh*HD + sr)*SS + su*8;  // + kt*64
  int pbase = w*1024;

  bf16x8 kreg = *(const bf16x8*)kgb;   // tile 0
  bf16x8 vreg = *(const bf16x8*)vgb;

  #pragma unroll 1
  for (int half = 0; half < 2; half++) {
    int qt2 = half ? (7 - ip) : ip;
    int last = 2*qt2 + 1;

    // Q fragments for this half: row = w*16+lq within 128-row tile
    const u16* qbase = Q + ((size_t)bh*SS + qt2*128 + w*16 + lq)*HD;
    bf16x8 qa0 = *(const bf16x8*)(qbase + g*8);
    bf16x8 qa1 = *(const bf16x8*)(qbase + g*8 + 32);

    f32x4 o[4];
    #pragma unroll
    for (int nb=0;nb<4;nb++) o[nb] = (f32x4){0.f,0.f,0.f,0.f};
    float mrun[4], lrun[4];
    #pragma unroll
    for (int r=0;r<4;r++) { mrun[r] = -1e30f; lrun[r] = 0.f; }

    #pragma unroll 1
    for (int kt = 0; kt <= last; kt++) {
      __syncthreads();   // prior iter's LDS reads complete
      *(bf16x8*)&Ks[kw] = kreg;
      *(bf16x8*)&Vs[kw] = vreg;
      __syncthreads();
      if (kt < last) {   // prefetch next tile; latency hides under compute below
        kreg = *(const bf16x8*)(kgb + (size_t)(kt+1)*64*HD);
        vreg = *(const bf16x8*)(vgb + (kt+1)*64);
      } else if (half == 0) {  // prefetch tile 0 for the second q-tile
        kreg = *(const bf16x8*)kgb;
        vreg = *(const bf16x8*)vgb;
      }
      // wave-uniform skip: tile entirely above this wave's rows
      if (kt*64 > qt2*128 + w*16 + 15) continue;

      // ---- S = Q K^T ----
      f32x4 s[4];
      #pragma unroll
      for (int nb=0;nb<4;nb++) s[nb] = (f32x4){0.f,0.f,0.f,0.f};
      #pragma unroll
      for (int ks=0; ks<2; ks++) {
        bf16x8 aq = ks ? qa1 : qa0;
        #pragma unroll
        for (int nb=0;nb<4;nb++) {
          bf16x8 kb = *(const bf16x8*)&Ks[(lq + 16*nb)*64 + (((g + 4*ks) ^ l7) << 3)];
          s[nb] = __builtin_amdgcn_mfma_f32_16x16x32_bf16(aq, kb, s[nb], 0, 0, 0);
        }
      }

      // ---- mask + online softmax ----
      bool diag = (kt*64 + 63 > qt2*128 + w*16);   // wave-uniform
      #pragma unroll
      for (int r=0;r<4;r++) {
        int qrow = qt2*128 + w*16 + g*4 + r;
        if (diag) {
          #pragma unroll
          for (int nb=0;nb<4;nb++)
            if (kt*64 + lq + 16*nb > qrow) s[nb][r] = -1e30f;
        }
        float rm = fmaxf(fmaxf(s[0][r], s[1][r]), fmaxf(s[2][r], s[3][r]));
        #pragma unroll
        for (int off=1; off<16; off<<=1) rm = fmaxf(rm, __shfl_xor(rm, off));
        float mnew = fmaxf(mrun[r], rm);
        float corr = __expf(mrun[r] - mnew);
        float psum = 0.f;
        int mrow = g*4 + r;
        #pragma unroll
        for (int nb=0;nb<4;nb++) {
          float p = __expf(s[nb][r] - mnew);
          psum += p;
          Ps[pbase + mrow*64 + ((((lq>>3) + 2*nb) ^ (mrow&7)) << 3) + l7] = f2bf(p);
        }
        #pragma unroll
        for (int off=1; off<16; off<<=1) psum += __shfl_xor(psum, off);
        lrun[r] = lrun[r]*corr + psum;
        mrun[r] = mnew;
        #pragma unroll
        for (int nb=0;nb<4;nb++) o[nb][r] *= corr;
      }

      // ---- O += P V ----
      #pragma unroll
      for (int ks=0; ks<2; ks++) {
        bf16x8 pa = *(const bf16x8*)&Ps[pbase + lq*64 + (((g + 4*ks) ^ l7) << 3)];
        #pragma unroll
        for (int nb=0;nb<4;nb++) {
          bf16x8 vb = *(const bf16x8*)&Vs[(lq + 16*nb)*64 + (((g + 4*ks) ^ l7) << 3)];
          o[nb] = __builtin_amdgcn_mfma_f32_16x16x32_bf16(pa, vb, o[nb], 0, 0, 0);
        }
      }
    }

    // ---- epilogue for this half: ctx bf16 (b, s, D) ----
    #pragma unroll
    for (int r=0;r<4;r++) {
      float inv = 1.f / lrun[r];
      int qrow = qt2*128 + w*16 + g*4 + r;
      u16* cp = ctxb + ((size_t)b*SS + qrow)*DM + h*HD;
      #pragma unroll
      for (int nb=0;nb<4;nb++) cp[lq + 16*nb] = f2bf(o[nb][r] * inv);
    }
  }
}

// ---------------- LayerNorm in-place on x, dual write (f32 + bf16) ----------------
__global__ __launch_bounds__(256) void k_ln(
    float* __restrict__ x, const float* __restrict__ g,
    const float* __restrict__ b, u16* __restrict__ xb) {
  int row = blockIdx.x*4 + (threadIdx.x>>6);
  int lane = threadIdx.x & 63;
  float* xr = x + (size_t)row*DM;
  float vals[8]; float s1=0.f, s2=0.f;
  #pragma unroll
  for (int u=0;u<8;u++){ float vv = xr[lane + 64*u]; vals[u]=vv; s1+=vv; s2+=vv*vv; }
  #pragma unroll
  for (int off=1; off<64; off<<=1){ s1 += __shfl_xor(s1,off); s2 += __shfl_xor(s2,off); }
  float mu  = s1 * (1.0f/DM);
  float var = s2 * (1.0f/DM) - mu*mu;
  float inv = rsqrtf(var + 1e-5f);
  u16* xbr = xb + (size_t)row*DM;
  #pragma unroll
  for (int u=0;u<8;u++){
    int c = lane+64*u;
    float vv = (vals[u]-mu)*inv*g[c] + b[c];
    xr[c] = vv;
    xbr[c] = f2bf(vv);
  }
}

// ---------------- head: out = 1.5*tanh(x@w^T + b) ----------------
__global__ __launch_bounds__(256) void k_head(
    const float* __restrict__ x, const float* __restrict__ w,
    const float* __restrict__ b, float* __restrict__ out) {
  int row = blockIdx.x*4 + (threadIdx.x>>6);
  int lane = threadIdx.x & 63;
  const float* xr = x + (size_t)row*DM;
  float acc = 0.f;
  #pragma unroll
  for (int u=0;u<8;u++) acc += xr[lane+64*u]*w[lane+64*u];
  #pragma unroll
  for (int off=1; off<64; off<<=1) acc += __shfl_xor(acc,off);
  if (lane == 0) out[row] = 1.5f * tanhf(acc + b[0]);
}

extern "C" void kernel_launch(void* const* d_in, const int* in_sizes, int n_in,
                              void* d_out, int out_size, void* d_ws, size_t ws_size,
                              hipStream_t stream) {
  (void)in_sizes; (void)n_in; (void)out_size; (void)ws_size;
  const float* feat      = (const float*)d_in[0];
  const float* hist_w    = (const float*)d_in[1];
  const float* hist_b    = (const float*)d_in[2];
  const float* query_w   = (const float*)d_in[3];
  const float* query_b   = (const float*)d_in[4];
  const float* in_proj_w = (const float*)d_in[5];
  const float* in_proj_b = (const float*)d_in[6];
  const float* attn_w    = (const float*)d_in[7];
  const float* attn_b    = (const float*)d_in[8];
  const float* ln_g      = (const float*)d_in[9];
  const float* ln_b      = (const float*)d_in[10];
  const float* out_w     = (const float*)d_in[11];
  const float* out_b     = (const float*)d_in[12];
  float* out = (float*)d_out;

  float* ws = (float*)d_ws;
  const size_t P = (size_t)NROWS * DM;   // 8.39M elems
  float* x    = ws;                      // fp32 residual stream
  u16* xb     = (u16*)(ws + P);          // bf16 x
  u16* histb  = xb + P;                  // bf16 history (both layers)
  u16* ctxb   = histb + P;               // bf16 attention context
  u16* qbf    = ctxb + P;                // bf16 Q (b,h,s,d) prescaled
  u16* kbf    = qbf + P;                 // bf16 K (b,h,s,d)
  u16* vtb    = kbf + P;                 // bf16 V^T (b,h,d,s)
  u16* wipb   = vtb + P;                 // bf16 in_proj_w (2*1536*512)
  u16* wob    = wipb + (size_t)2*3*DM*DM;// bf16 attn_out_w (2*512*512)

  {
    int n4i = 2*3*DM*DM/4, n4o = 2*DM*DM/4;
    k_f2bf_v<<<(n4i+255)/256, 256, 0, stream>>>(in_proj_w, wipb, n4i);
    k_f2bf_v<<<(n4o+255)/256, 256, 0, stream>>>(attn_w, wob, n4o);
  }
  k_input_proj<<<NROWS, 256, 0, stream>>>(feat, hist_w, hist_b, query_w, query_b, histb, x, xb);

  for (int l = 0; l < 2; l++) {
    const u16* wq  = wipb + (size_t)l*3*DM*DM;
    const u16* wkv = wq + (size_t)DM*DM;
    const float* bq  = in_proj_b + (size_t)l*3*DM;
    const float* bkv = bq + DM;
    k_bgemm<1><<<dim3(4, 128), 256, 0, stream>>>(xb,    wq,  bq,  nullptr, qbf, nullptr);
    k_bgemm<2><<<dim3(8, 128), 256, 0, stream>>>(histb, wkv, bkv, nullptr, kbf, vtb);
    dim3 ga(4, BB*NH);
    k_attn_mfma<<<ga, 512, 0, stream>>>(qbf, kbf, vtb, ctxb);
    const u16* wo = wob + (size_t)l*DM*DM;
    const float* bo = attn_b + (size_t)l*DM;
    k_bgemm<3><<<dim3(4, 128), 256, 0, stream>>>(ctxb, wo, bo, x, nullptr, nullptr);
    k_ln<<<NROWS/4, 256, 0, stream>>>(x, ln_g + (size_t)l*DM, ln_b + (size_t)l*DM, xb);
  }
  k_head<<<NROWS/4, 256, 0, stream>>>(x, out_w, out_b, out);
}

// Round 11
// 422.015 us; speedup vs baseline: 8.0264x; 1.0707x over previous
//
#include <hip/hip_runtime.h>
#include <math.h>

#define DM 512
#define NH 8
#define HD 64
#define BB 16
#define SS 1024
#define NROWS (BB*SS)   // 16384
#define IND 16
#define KD 512

typedef unsigned short u16;
typedef __attribute__((ext_vector_type(8))) short bf16x8;
typedef __attribute__((ext_vector_type(4))) float f32x4;

// round-to-nearest-even f32 -> bf16 (finite inputs)
static __device__ __forceinline__ u16 f2bf(float f) {
  union { float f; unsigned int u; } v; v.f = f;
  unsigned int r = v.u + 0x7FFFu + ((v.u >> 16) & 1u);
  return (u16)(r >> 16);
}

static __device__ __forceinline__ float dot4(float4 a, float4 b) {
  return a.x*b.x + a.y*b.y + a.z*b.z + a.w*b.w;
}

// ---------------- weight f32 -> bf16 (vectorized) ----------------
__global__ __launch_bounds__(256) void k_f2bf_v(const float* __restrict__ in,
                                                u16* __restrict__ out, int n4) {
  int i = blockIdx.x * 256 + threadIdx.x;
  if (i < n4) {
    float4 v = ((const float4*)in)[i];
    ushort4 p;
    p.x = f2bf(v.x); p.y = f2bf(v.y); p.z = f2bf(v.z); p.w = f2bf(v.w);
    ((ushort4*)out)[i] = p;
  }
}

// ---------------- input projections: hist(bf16), x(f32 + bf16) ----------------
// 1024 blocks x 256 thr; block = 16 rows; wave = 4 rows; lane = cols {lane*4, 256+lane*4}.
// Weights register-cached per 4-col chunk, reused across the wave's 4 rows.
__global__ __launch_bounds__(256) void k_input_proj(
    const float* __restrict__ feat, const float* __restrict__ hw, const float* __restrict__ hb,
    const float* __restrict__ qw, const float* __restrict__ qb,
    u16* __restrict__ histb, float* __restrict__ x, u16* __restrict__ xb) {
  int r0 = blockIdx.x * 16;
  int tid = threadIdx.x;
  int w = tid >> 6, lane = tid & 63;
  __shared__ float f[16][16];
  f[tid >> 4][tid & 15] = feat[(size_t)(r0 + (tid >> 4))*IND + (tid & 15)];
  __syncthreads();

  #pragma unroll
  for (int ch = 0; ch < 2; ch++) {
    int c0 = ch*256 + lane*4;
    // ---- hist projection ----
    {
      float4 wv[4][4];
      #pragma unroll
      for (int j=0;j<4;j++)
        #pragma unroll
        for (int kq=0;kq<4;kq++)
          wv[j][kq] = *(const float4*)(hw + (size_t)(c0+j)*IND + kq*4);
      float b0 = hb[c0], b1 = hb[c0+1], b2 = hb[c0+2], b3 = hb[c0+3];
      #pragma unroll
      for (int rr=0; rr<4; rr++) {
        int row = r0 + w*4 + rr;
        const float4* fr = (const float4*)f[w*4 + rr];
        float4 f0 = fr[0], f1 = fr[1], f2 = fr[2], f3 = fr[3];
        float v0 = b0 + dot4(wv[0][0],f0) + dot4(wv[0][1],f1) + dot4(wv[0][2],f2) + dot4(wv[0][3],f3);
        float v1 = b1 + dot4(wv[1][0],f0) + dot4(wv[1][1],f1) + dot4(wv[1][2],f2) + dot4(wv[1][3],f3);
        float v2 = b2 + dot4(wv[2][0],f0) + dot4(wv[2][1],f1) + dot4(wv[2][2],f2) + dot4(wv[2][3],f3);
        float v3 = b3 + dot4(wv[3][0],f0) + dot4(wv[3][1],f1) + dot4(wv[3][2],f2) + dot4(wv[3][3],f3);
        ushort4 hp; hp.x = f2bf(v0); hp.y = f2bf(v1); hp.z = f2bf(v2); hp.w = f2bf(v3);
        *(ushort4*)&histb[(size_t)row*DM + c0] = hp;
      }
    }
    // ---- query projection ----
    {
      float4 wv[4][4];
      #pragma unroll
      for (int j=0;j<4;j++)
        #pragma unroll
        for (int kq=0;kq<4;kq++)
          wv[j][kq] = *(const float4*)(qw + (size_t)(c0+j)*IND + kq*4);
      float b0 = qb[c0], b1 = qb[c0+1], b2 = qb[c0+2], b3 = qb[c0+3];
      #pragma unroll
      for (int rr=0; rr<4; rr++) {
        int row = r0 + w*4 + rr;
        const float4* fr = (const float4*)f[w*4 + rr];
        float4 f0 = fr[0], f1 = fr[1], f2 = fr[2], f3 = fr[3];
        float v0 = b0 + dot4(wv[0][0],f0) + dot4(wv[0][1],f1) + dot4(wv[0][2],f2) + dot4(wv[0][3],f3);
        float v1 = b1 + dot4(wv[1][0],f0) + dot4(wv[1][1],f1) + dot4(wv[1][2],f2) + dot4(wv[1][3],f3);
        float v2 = b2 + dot4(wv[2][0],f0) + dot4(wv[2][1],f1) + dot4(wv[2][2],f2) + dot4(wv[2][3],f3);
        float v3 = b3 + dot4(wv[3][0],f0) + dot4(wv[3][1],f1) + dot4(wv[3][2],f2) + dot4(wv[3][3],f3);
        float4 xv; xv.x = v0; xv.y = v1; xv.z = v2; xv.w = v3;
        *(float4*)&x[(size_t)row*DM + c0] = xv;
        ushort4 xp; xp.x = f2bf(v0); xp.y = f2bf(v1); xp.z = f2bf(v2); xp.w = f2bf(v3);
        *(ushort4*)&xb[(size_t)row*DM + c0] = xp;
      }
    }
  }
}

// ---------------- bf16 MFMA GEMM: C = A[M,512] @ W[N,512]^T + bias ----------------
template<int EPI>
__global__ __launch_bounds__(256) void k_bgemm(
    const u16* __restrict__ A, const u16* __restrict__ Wb,
    const float* __restrict__ bias,
    float* __restrict__ Cf, u16* __restrict__ C0h, u16* __restrict__ C1h) {
  __shared__ u16 As[128*64];
  __shared__ u16 Bs[128*64];
  int bm = blockIdx.y * 128, bn = blockIdx.x * 128;
  int tid = threadIdx.x;
  int w = tid >> 6, lane = tid & 63;
  int wm = (w >> 1) * 64, wn = (w & 1) * 64;
  int lq = lane & 15, g = lane >> 4, l7 = lq & 7;

  int srow = tid >> 1;
  int su0 = (tid & 1) * 4;
  const u16* Ag = A  + (size_t)(bm + srow)*KD + su0*8;
  const u16* Bg = Wb + (size_t)(bn + srow)*KD + su0*8;
  int sw[4];
  #pragma unroll
  for (int i=0;i<4;i++) sw[i] = srow*64 + (((su0+i) ^ (srow&7)) << 3);

  f32x4 acc[4][4];
  #pragma unroll
  for (int mf=0;mf<4;mf++)
    #pragma unroll
    for (int nf=0;nf<4;nf++) acc[mf][nf] = (f32x4){0.f,0.f,0.f,0.f};

  #pragma unroll 1
  for (int k0 = 0; k0 < KD; k0 += 64) {
    bf16x8 ar[4], br[4];
    #pragma unroll
    for (int i=0;i<4;i++) {
      ar[i] = *(const bf16x8*)(Ag + k0 + i*8);
      br[i] = *(const bf16x8*)(Bg + k0 + i*8);
    }
    __syncthreads();
    #pragma unroll
    for (int i=0;i<4;i++) { *(bf16x8*)&As[sw[i]] = ar[i]; *(bf16x8*)&Bs[sw[i]] = br[i]; }
    __syncthreads();
    #pragma unroll
    for (int ks=0; ks<2; ks++) {
      int un = ((g + 4*ks) ^ l7) << 3;
      bf16x8 af[4], bfr[4];
      #pragma unroll
      for (int mf=0;mf<4;mf++) af[mf]  = *(const bf16x8*)&As[(wm + mf*16 + lq)*64 + un];
      #pragma unroll
      for (int nf=0;nf<4;nf++) bfr[nf] = *(const bf16x8*)&Bs[(wn + nf*16 + lq)*64 + un];
      #pragma unroll
      for (int mf=0;mf<4;mf++)
        #pragma unroll
        for (int nf=0;nf<4;nf++)
          acc[mf][nf] = __builtin_amdgcn_mfma_f32_16x16x32_bf16(af[mf], bfr[nf], acc[mf][nf], 0, 0, 0);
    }
  }

  float fb[4];
  #pragma unroll
  for (int nf=0;nf<4;nf++) fb[nf] = bias[bn + wn + nf*16 + lq];
  int m0 = bm + wm + g*4;
  int n0 = bn + wn + lq;

  if (EPI == 1 || (EPI == 2 && bn < 512)) {
    const float sc = (EPI == 1) ? 0.125f : 1.0f;
    #pragma unroll
    for (int mf=0;mf<4;mf++) {
      int mb = m0 + mf*16;
      int b = mb >> 10, s = mb & 1023;
      #pragma unroll
      for (int nf=0;nf<4;nf++) {
        int n = n0 + nf*16;
        int h = (n >> 6) & 7, d = n & 63;
        u16* dst = C0h + (((size_t)(b*NH + h))*SS + s)*HD + d;
        #pragma unroll
        for (int r=0;r<4;r++) dst[r*HD] = f2bf((acc[mf][nf][r] + fb[nf]) * sc);
      }
    }
  } else if (EPI == 2) {
    #pragma unroll
    for (int mf=0;mf<4;mf++) {
      int mb = m0 + mf*16;
      int b = mb >> 10, s = mb & 1023;
      #pragma unroll
      for (int nf=0;nf<4;nf++) {
        int n = n0 + nf*16 - 512;
        int h = n >> 6, d = n & 63;
        ushort4 pk;
        pk.x = f2bf(acc[mf][nf][0] + fb[nf]);
        pk.y = f2bf(acc[mf][nf][1] + fb[nf]);
        pk.z = f2bf(acc[mf][nf][2] + fb[nf]);
        pk.w = f2bf(acc[mf][nf][3] + fb[nf]);
        *(ushort4*)&C1h[(((size_t)(b*NH + h))*HD + d)*SS + s] = pk;
      }
    }
  } else {
    #pragma unroll
    for (int mf=0;mf<4;mf++) {
      #pragma unroll
      for (int r=0;r<4;r++) {
        int m = m0 + mf*16 + r;
        #pragma unroll
        for (int nf=0;nf<4;nf++) {
          int n = n0 + nf*16;
          Cf[(size_t)m*DM + n] = acc[mf][nf][r] + fb[nf] + Cf[(size_t)m*DM + n];
        }
      }
    }
  }
}

// ---------------- flash attention, bf16 MFMA, causal; 512 thr, paired q-tiles ----------------
// blockIdx.x = i (0..3): processes 128-row q-tile i then q-tile 7-i (18 K-iters uniform).
__global__ __launch_bounds__(512) void k_attn_mfma(
    const u16* __restrict__ Q, const u16* __restrict__ K,
    const u16* __restrict__ Vt, u16* __restrict__ ctxb) {
  int ip = blockIdx.x;          // 0..3 pair index
  int bh = blockIdx.y;          // 0..127
  int b = bh >> 3, h = bh & 7;
  int tid = threadIdx.x;
  int w = tid >> 6, lane = tid & 63;
  int lq = lane & 15, g = lane >> 4;
  int l7 = lq & 7;

  __shared__ u16 Ks[4096];   // [64 kk][64 d], 16B-unit XOR swizzle (row&7)
  __shared__ u16 Vs[4096];   // [64 d][64 kk], same swizzle
  __shared__ u16 Ps[8192];   // 8 waves x 16x64 strip, same swizzle

  int sr = tid >> 3, su = tid & 7;
  int kw = sr*64 + ((su ^ (sr&7)) << 3);
  const u16* kgb = K + ((size_t)bh*SS + sr)*HD + su*8;   // + kt*64*HD
  const u16* vgb = Vt + ((size_t)bh*HD + sr)*SS + su*8;  // + kt*64
  int pbase = w*1024;

  bf16x8 kreg = *(const bf16x8*)kgb;   // tile 0
  bf16x8 vreg = *(const bf16x8*)vgb;

  #pragma unroll 1
  for (int half = 0; half < 2; half++) {
    int qt2 = half ? (7 - ip) : ip;
    int last = 2*qt2 + 1;

    const u16* qbase = Q + ((size_t)bh*SS + qt2*128 + w*16 + lq)*HD;
    bf16x8 qa0 = *(const bf16x8*)(qbase + g*8);
    bf16x8 qa1 = *(const bf16x8*)(qbase + g*8 + 32);

    f32x4 o[4];
    #pragma unroll
    for (int nb=0;nb<4;nb++) o[nb] = (f32x4){0.f,0.f,0.f,0.f};
    float mrun[4], lrun[4];
    #pragma unroll
    for (int r=0;r<4;r++) { mrun[r] = -1e30f; lrun[r] = 0.f; }

    #pragma unroll 1
    for (int kt = 0; kt <= last; kt++) {
      __syncthreads();   // prior iter's LDS reads complete
      *(bf16x8*)&Ks[kw] = kreg;
      *(bf16x8*)&Vs[kw] = vreg;
      __syncthreads();
      if (kt < last) {   // prefetch next tile
        kreg = *(const bf16x8*)(kgb + (size_t)(kt+1)*64*HD);
        vreg = *(const bf16x8*)(vgb + (kt+1)*64);
      } else if (half == 0) {  // prefetch tile 0 for the second q-tile
        kreg = *(const bf16x8*)kgb;
        vreg = *(const bf16x8*)vgb;
      }
      if (kt*64 > qt2*128 + w*16 + 15) continue;

      // ---- S = Q K^T ----
      f32x4 s[4];
      #pragma unroll
      for (int nb=0;nb<4;nb++) s[nb] = (f32x4){0.f,0.f,0.f,0.f};
      #pragma unroll
      for (int ks=0; ks<2; ks++) {
        bf16x8 aq = ks ? qa1 : qa0;
        #pragma unroll
        for (int nb=0;nb<4;nb++) {
          bf16x8 kb = *(const bf16x8*)&Ks[(lq + 16*nb)*64 + (((g + 4*ks) ^ l7) << 3)];
          s[nb] = __builtin_amdgcn_mfma_f32_16x16x32_bf16(aq, kb, s[nb], 0, 0, 0);
        }
      }

      // ---- mask + online softmax ----
      bool diag = (kt*64 + 63 > qt2*128 + w*16);   // wave-uniform
      #pragma unroll
      for (int r=0;r<4;r++) {
        int qrow = qt2*128 + w*16 + g*4 + r;
        if (diag) {
          #pragma unroll
          for (int nb=0;nb<4;nb++)
            if (kt*64 + lq + 16*nb > qrow) s[nb][r] = -1e30f;
        }
        float rm = fmaxf(fmaxf(s[0][r], s[1][r]), fmaxf(s[2][r], s[3][r]));
        #pragma unroll
        for (int off=1; off<16; off<<=1) rm = fmaxf(rm, __shfl_xor(rm, off));
        float mnew = fmaxf(mrun[r], rm);
        float corr = __expf(mrun[r] - mnew);
        float psum = 0.f;
        int mrow = g*4 + r;
        #pragma unroll
        for (int nb=0;nb<4;nb++) {
          float p = __expf(s[nb][r] - mnew);
          psum += p;
          Ps[pbase + mrow*64 + ((((lq>>3) + 2*nb) ^ (mrow&7)) << 3) + l7] = f2bf(p);
        }
        #pragma unroll
        for (int off=1; off<16; off<<=1) psum += __shfl_xor(psum, off);
        lrun[r] = lrun[r]*corr + psum;
        mrun[r] = mnew;
        #pragma unroll
        for (int nb=0;nb<4;nb++) o[nb][r] *= corr;
      }

      // ---- O += P V ----
      #pragma unroll
      for (int ks=0; ks<2; ks++) {
        bf16x8 pa = *(const bf16x8*)&Ps[pbase + lq*64 + (((g + 4*ks) ^ l7) << 3)];
        #pragma unroll
        for (int nb=0;nb<4;nb++) {
          bf16x8 vb = *(const bf16x8*)&Vs[(lq + 16*nb)*64 + (((g + 4*ks) ^ l7) << 3)];
          o[nb] = __builtin_amdgcn_mfma_f32_16x16x32_bf16(pa, vb, o[nb], 0, 0, 0);
        }
      }
    }

    // ---- epilogue for this half ----
    #pragma unroll
    for (int r=0;r<4;r++) {
      float inv = 1.f / lrun[r];
      int qrow = qt2*128 + w*16 + g*4 + r;
      u16* cp = ctxb + ((size_t)b*SS + qrow)*DM + h*HD;
      #pragma unroll
      for (int nb=0;nb<4;nb++) cp[lq + 16*nb] = f2bf(o[nb][r] * inv);
    }
  }
}

// ---------------- LayerNorm in-place on x, dual write (f32 + bf16) ----------------
__global__ __launch_bounds__(256) void k_ln(
    float* __restrict__ x, const float* __restrict__ g,
    const float* __restrict__ b, u16* __restrict__ xb) {
  int row = blockIdx.x*4 + (threadIdx.x>>6);
  int lane = threadIdx.x & 63;
  float* xr = x + (size_t)row*DM;
  float vals[8]; float s1=0.f, s2=0.f;
  #pragma unroll
  for (int u=0;u<8;u++){ float vv = xr[lane + 64*u]; vals[u]=vv; s1+=vv; s2+=vv*vv; }
  #pragma unroll
  for (int off=1; off<64; off<<=1){ s1 += __shfl_xor(s1,off); s2 += __shfl_xor(s2,off); }
  float mu  = s1 * (1.0f/DM);
  float var = s2 * (1.0f/DM) - mu*mu;
  float inv = rsqrtf(var + 1e-5f);
  u16* xbr = xb + (size_t)row*DM;
  #pragma unroll
  for (int u=0;u<8;u++){
    int c = lane+64*u;
    float vv = (vals[u]-mu)*inv*g[c] + b[c];
    xr[c] = vv;
    xbr[c] = f2bf(vv);
  }
}

// ---------------- head: out = 1.5*tanh(x@w^T + b) ----------------
__global__ __launch_bounds__(256) void k_head(
    const float* __restrict__ x, const float* __restrict__ w,
    const float* __restrict__ b, float* __restrict__ out) {
  int row = blockIdx.x*4 + (threadIdx.x>>6);
  int lane = threadIdx.x & 63;
  const float* xr = x + (size_t)row*DM;
  float acc = 0.f;
  #pragma unroll
  for (int u=0;u<8;u++) acc += xr[lane+64*u]*w[lane+64*u];
  #pragma unroll
  for (int off=1; off<64; off<<=1) acc += __shfl_xor(acc,off);
  if (lane == 0) out[row] = 1.5f * tanhf(acc + b[0]);
}

extern "C" void kernel_launch(void* const* d_in, const int* in_sizes, int n_in,
                              void* d_out, int out_size, void* d_ws, size_t ws_size,
                              hipStream_t stream) {
  (void)in_sizes; (void)n_in; (void)out_size; (void)ws_size;
  const float* feat      = (const float*)d_in[0];
  const float* hist_w    = (const float*)d_in[1];
  const float* hist_b    = (const float*)d_in[2];
  const float* query_w   = (const float*)d_in[3];
  const float* query_b   = (const float*)d_in[4];
  const float* in_proj_w = (const float*)d_in[5];
  const float* in_proj_b = (const float*)d_in[6];
  const float* attn_w    = (const float*)d_in[7];
  const float* attn_b    = (const float*)d_in[8];
  const float* ln_g      = (const float*)d_in[9];
  const float* ln_b      = (const float*)d_in[10];
  const float* out_w     = (const float*)d_in[11];
  const float* out_b     = (const float*)d_in[12];
  float* out = (float*)d_out;

  float* ws = (float*)d_ws;
  const size_t P = (size_t)NROWS * DM;   // 8.39M elems
  float* x    = ws;                      // fp32 residual stream
  u16* xb     = (u16*)(ws + P);          // bf16 x
  u16* histb  = xb + P;                  // bf16 history (both layers)
  u16* ctxb   = histb + P;               // bf16 attention context
  u16* qbf    = ctxb + P;                // bf16 Q (b,h,s,d) prescaled
  u16* kbf    = qbf + P;                 // bf16 K (b,h,s,d)
  u16* vtb    = kbf + P;                 // bf16 V^T (b,h,d,s)
  u16* wipb   = vtb + P;                 // bf16 in_proj_w (2*1536*512)
  u16* wob    = wipb + (size_t)2*3*DM*DM;// bf16 attn_out_w (2*512*512)

  {
    int n4i = 2*3*DM*DM/4, n4o = 2*DM*DM/4;
    k_f2bf_v<<<(n4i+255)/256, 256, 0, stream>>>(in_proj_w, wipb, n4i);
    k_f2bf_v<<<(n4o+255)/256, 256, 0, stream>>>(attn_w, wob, n4o);
  }
  k_input_proj<<<NROWS/16, 256, 0, stream>>>(feat, hist_w, hist_b, query_w, query_b, histb, x, xb);

  for (int l = 0; l < 2; l++) {
    const u16* wq  = wipb + (size_t)l*3*DM*DM;
    const u16* wkv = wq + (size_t)DM*DM;
    const float* bq  = in_proj_b + (size_t)l*3*DM;
    const float* bkv = bq + DM;
    k_bgemm<1><<<dim3(4, 128), 256, 0, stream>>>(xb,    wq,  bq,  nullptr, qbf, nullptr);
    k_bgemm<2><<<dim3(8, 128), 256, 0, stream>>>(histb, wkv, bkv, nullptr, kbf, vtb);
    dim3 ga(4, BB*NH);
    k_attn_mfma<<<ga, 512, 0, stream>>>(qbf, kbf, vtb, ctxb);
    const u16* wo = wob + (size_t)l*DM*DM;
    const float* bo = attn_b + (size_t)l*DM;
    k_bgemm<3><<<dim3(4, 128), 256, 0, stream>>>(ctxb, wo, bo, x, nullptr, nullptr);
    k_ln<<<NROWS/4, 256, 0, stream>>>(x, ln_g + (size_t)l*DM, ln_b + (size_t)l*DM, xb);
  }
  k_head<<<NROWS/4, 256, 0, stream>>>(x, out_w, out_b, out);
}

// Round 13
// 412.708 us; speedup vs baseline: 8.2074x; 1.0226x over previous
//
#include <hip/hip_runtime.h>
#include <math.h>

#define DM 512
#define NH 8
#define HD 64
#define BB 16
#define SS 1024
#define NROWS (BB*SS)   // 16384
#define IND 16
#define KD 512

typedef unsigned short u16;
typedef __attribute__((ext_vector_type(8))) short bf16x8;
typedef __attribute__((ext_vector_type(4))) float f32x4;

// round-to-nearest-even f32 -> bf16 (finite inputs)
static __device__ __forceinline__ u16 f2bf(float f) {
  union { float f; unsigned int u; } v; v.f = f;
  unsigned int r = v.u + 0x7FFFu + ((v.u >> 16) & 1u);
  return (u16)(r >> 16);
}

static __device__ __forceinline__ float dot4(float4 a, float4 b) {
  return a.x*b.x + a.y*b.y + a.z*b.z + a.w*b.w;
}

// async global->LDS 16B DMA (lane l writes LDS base + l*16)
#define GLOAD_LDS16(gp, lp)                                                  \
  __builtin_amdgcn_global_load_lds(                                          \
      (const __attribute__((address_space(1))) void*)(gp),                   \
      (__attribute__((address_space(3))) void*)(lp), 16, 0, 0)

// ---------------- weight f32 -> bf16 (vectorized) ----------------
__global__ __launch_bounds__(256) void k_f2bf_v(const float* __restrict__ in,
                                                u16* __restrict__ out, int n4) {
  int i = blockIdx.x * 256 + threadIdx.x;
  if (i < n4) {
    float4 v = ((const float4*)in)[i];
    ushort4 p;
    p.x = f2bf(v.x); p.y = f2bf(v.y); p.z = f2bf(v.z); p.w = f2bf(v.w);
    ((ushort4*)out)[i] = p;
  }
}

// ---------------- input projections: hist(bf16), x(f32 + bf16) ----------------
__global__ __launch_bounds__(256) void k_input_proj(
    const float* __restrict__ feat, const float* __restrict__ hw, const float* __restrict__ hb,
    const float* __restrict__ qw, const float* __restrict__ qb,
    u16* __restrict__ histb, float* __restrict__ x, u16* __restrict__ xb) {
  int r0 = blockIdx.x * 16;
  int tid = threadIdx.x;
  int w = tid >> 6, lane = tid & 63;
  __shared__ float f[16][16];
  f[tid >> 4][tid & 15] = feat[(size_t)(r0 + (tid >> 4))*IND + (tid & 15)];
  __syncthreads();

  #pragma unroll
  for (int ch = 0; ch < 2; ch++) {
    int c0 = ch*256 + lane*4;
    // ---- hist projection ----
    {
      float4 wv[4][4];
      #pragma unroll
      for (int j=0;j<4;j++)
        #pragma unroll
        for (int kq=0;kq<4;kq++)
          wv[j][kq] = *(const float4*)(hw + (size_t)(c0+j)*IND + kq*4);
      float b0 = hb[c0], b1 = hb[c0+1], b2 = hb[c0+2], b3 = hb[c0+3];
      #pragma unroll
      for (int rr=0; rr<4; rr++) {
        int row = r0 + w*4 + rr;
        const float4* fr = (const float4*)f[w*4 + rr];
        float4 f0 = fr[0], f1 = fr[1], f2 = fr[2], f3 = fr[3];
        float v0 = b0 + dot4(wv[0][0],f0) + dot4(wv[0][1],f1) + dot4(wv[0][2],f2) + dot4(wv[0][3],f3);
        float v1 = b1 + dot4(wv[1][0],f0) + dot4(wv[1][1],f1) + dot4(wv[1][2],f2) + dot4(wv[1][3],f3);
        float v2 = b2 + dot4(wv[2][0],f0) + dot4(wv[2][1],f1) + dot4(wv[2][2],f2) + dot4(wv[2][3],f3);
        float v3 = b3 + dot4(wv[3][0],f0) + dot4(wv[3][1],f1) + dot4(wv[3][2],f2) + dot4(wv[3][3],f3);
        ushort4 hp; hp.x = f2bf(v0); hp.y = f2bf(v1); hp.z = f2bf(v2); hp.w = f2bf(v3);
        *(ushort4*)&histb[(size_t)row*DM + c0] = hp;
      }
    }
    // ---- query projection ----
    {
      float4 wv[4][4];
      #pragma unroll
      for (int j=0;j<4;j++)
        #pragma unroll
        for (int kq=0;kq<4;kq++)
          wv[j][kq] = *(const float4*)(qw + (size_t)(c0+j)*IND + kq*4);
      float b0 = qb[c0], b1 = qb[c0+1], b2 = qb[c0+2], b3 = qb[c0+3];
      #pragma unroll
      for (int rr=0; rr<4; rr++) {
        int row = r0 + w*4 + rr;
        const float4* fr = (const float4*)f[w*4 + rr];
        float4 f0 = fr[0], f1 = fr[1], f2 = fr[2], f3 = fr[3];
        float v0 = b0 + dot4(wv[0][0],f0) + dot4(wv[0][1],f1) + dot4(wv[0][2],f2) + dot4(wv[0][3],f3);
        float v1 = b1 + dot4(wv[1][0],f0) + dot4(wv[1][1],f1) + dot4(wv[1][2],f2) + dot4(wv[1][3],f3);
        float v2 = b2 + dot4(wv[2][0],f0) + dot4(wv[2][1],f1) + dot4(wv[2][2],f2) + dot4(wv[2][3],f3);
        float v3 = b3 + dot4(wv[3][0],f0) + dot4(wv[3][1],f1) + dot4(wv[3][2],f2) + dot4(wv[3][3],f3);
        float4 xv; xv.x = v0; xv.y = v1; xv.z = v2; xv.w = v3;
        *(float4*)&x[(size_t)row*DM + c0] = xv;
        ushort4 xp; xp.x = f2bf(v0); xp.y = f2bf(v1); xp.z = f2bf(v2); xp.w = f2bf(v3);
        *(ushort4*)&xb[(size_t)row*DM + c0] = xp;
      }
    }
  }
}

// ---------------- bf16 MFMA GEMM: C = A[M,512] @ W[N,512]^T + bias ----------------
// 128x128 tile, 4 waves, BK=64. Staging via global_load_lds (16B DMA) into
// double-buffered LDS; next tile's DMA issued BEFORE computing current tile
// (latency hides under 32 MFMAs); ONE barrier per K-step.
// Swizzle preserved by rule "linear dest + inverse-swizzled source":
//   lane l writes LDS row (base+ l>>3), unit l&7; global source unit = (l&7)^(l>>3)
//   -> LDS[row][u] holds global unit u^(row&7)  (same image as before).
template<int EPI>
__global__ __launch_bounds__(256) void k_bgemm(
    const u16* __restrict__ A, const u16* __restrict__ Wb,
    const float* __restrict__ bias,
    float* __restrict__ Cf, u16* __restrict__ C0h, u16* __restrict__ C1h) {
  __shared__ u16 As[2][128*64];
  __shared__ u16 Bs[2][128*64];
  int bm = blockIdx.y * 128, bn = blockIdx.x * 128;
  int tid = threadIdx.x;
  int wv = tid >> 6, lane = tid & 63;
  int wm = (wv >> 1) * 64, wn = (wv & 1) * 64;
  int lq = lane & 15, g = lane >> 4, l7 = lq & 7;

  // DMA staging mapping
  int rsub = lane >> 3;            // 0..7 (row within 8-row stripe)
  int sug  = (lane & 7) ^ rsub;    // inverse-swizzled source 16B-unit
  const u16* Ag = A  + (size_t)(bm + wv*32 + rsub)*KD + sug*8;
  const u16* Bg = Wb + (size_t)(bn + wv*32 + rsub)*KD + sug*8;

  f32x4 acc[4][4];
  #pragma unroll
  for (int mf=0;mf<4;mf++)
    #pragma unroll
    for (int nf=0;nf<4;nf++) acc[mf][nf] = (f32x4){0.f,0.f,0.f,0.f};

  // prologue: stage tile 0 into buffer 0
  #pragma unroll
  for (int j=0;j<4;j++) {
    GLOAD_LDS16(Ag + (size_t)j*8*KD, &As[0][(wv*32 + j*8)*64]);
    GLOAD_LDS16(Bg + (size_t)j*8*KD, &Bs[0][(wv*32 + j*8)*64]);
  }
  __syncthreads();   // vmcnt drain: tile 0 resident

  #pragma unroll 1
  for (int t = 0; t < 8; t++) {
    int cur = t & 1;
    if (t < 7) {     // issue next tile's DMA into the other buffer (no wait)
      int nxt = cur ^ 1;
      int k0n = (t+1)*64;
      #pragma unroll
      for (int j=0;j<4;j++) {
        GLOAD_LDS16(Ag + (size_t)j*8*KD + k0n, &As[nxt][(wv*32 + j*8)*64]);
        GLOAD_LDS16(Bg + (size_t)j*8*KD + k0n, &Bs[nxt][(wv*32 + j*8)*64]);
      }
    }
    const u16* Ac = As[cur];
    const u16* Bc = Bs[cur];
    #pragma unroll
    for (int ks=0; ks<2; ks++) {
      int un = ((g + 4*ks) ^ l7) << 3;
      bf16x8 af[4], bfr[4];
      #pragma unroll
      for (int mf=0;mf<4;mf++) af[mf]  = *(const bf16x8*)&Ac[(wm + mf*16 + lq)*64 + un];
      #pragma unroll
      for (int nf=0;nf<4;nf++) bfr[nf] = *(const bf16x8*)&Bc[(wn + nf*16 + lq)*64 + un];
      #pragma unroll
      for (int mf=0;mf<4;mf++)
        #pragma unroll
        for (int nf=0;nf<4;nf++)
          acc[mf][nf] = __builtin_amdgcn_mfma_f32_16x16x32_bf16(af[mf], bfr[nf], acc[mf][nf], 0, 0, 0);
    }
    // one barrier: (a) drains this iter's prefetch DMA (vmcnt0 before s_barrier),
    // (b) all waves done reading buf cur before it is re-staged next iter.
    __syncthreads();
  }

  float fb[4];
  #pragma unroll
  for (int nf=0;nf<4;nf++) fb[nf] = bias[bn + wn + nf*16 + lq];
  int m0 = bm + wm + g*4;
  int n0 = bn + wn + lq;

  if (EPI == 1 || (EPI == 2 && bn < 512)) {
    const float sc = (EPI == 1) ? 0.125f : 1.0f;
    #pragma unroll
    for (int mf=0;mf<4;mf++) {
      int mb = m0 + mf*16;
      int b = mb >> 10, s = mb & 1023;
      #pragma unroll
      for (int nf=0;nf<4;nf++) {
        int n = n0 + nf*16;
        int h = (n >> 6) & 7, d = n & 63;
        u16* dst = C0h + (((size_t)(b*NH + h))*SS + s)*HD + d;
        #pragma unroll
        for (int r=0;r<4;r++) dst[r*HD] = f2bf((acc[mf][nf][r] + fb[nf]) * sc);
      }
    }
  } else if (EPI == 2) {
    #pragma unroll
    for (int mf=0;mf<4;mf++) {
      int mb = m0 + mf*16;
      int b = mb >> 10, s = mb & 1023;
      #pragma unroll
      for (int nf=0;nf<4;nf++) {
        int n = n0 + nf*16 - 512;
        int h = n >> 6, d = n & 63;
        ushort4 pk;
        pk.x = f2bf(acc[mf][nf][0] + fb[nf]);
        pk.y = f2bf(acc[mf][nf][1] + fb[nf]);
        pk.z = f2bf(acc[mf][nf][2] + fb[nf]);
        pk.w = f2bf(acc[mf][nf][3] + fb[nf]);
        *(ushort4*)&C1h[(((size_t)(b*NH + h))*HD + d)*SS + s] = pk;
      }
    }
  } else {
    #pragma unroll
    for (int mf=0;mf<4;mf++) {
      #pragma unroll
      for (int r=0;r<4;r++) {
        int m = m0 + mf*16 + r;
        #pragma unroll
        for (int nf=0;nf<4;nf++) {
          int n = n0 + nf*16;
          Cf[(size_t)m*DM + n] = acc[mf][nf][r] + fb[nf] + Cf[(size_t)m*DM + n];
        }
      }
    }
  }
}

// ---------------- flash attention, bf16 MFMA, causal; 512 thr, paired q-tiles ----------------
// blockIdx.x = i (0..3): processes 128-row q-tile i then q-tile 7-i (18 K-iters uniform).
__global__ __launch_bounds__(512) void k_attn_mfma(
    const u16* __restrict__ Q, const u16* __restrict__ K,
    const u16* __restrict__ Vt, u16* __restrict__ ctxb) {
  int ip = blockIdx.x;          // 0..3 pair index
  int bh = blockIdx.y;          // 0..127
  int b = bh >> 3, h = bh & 7;
  int tid = threadIdx.x;
  int w = tid >> 6, lane = tid & 63;
  int lq = lane & 15, g = lane >> 4;
  int l7 = lq & 7;

  __shared__ u16 Ks[4096];   // [64 kk][64 d], 16B-unit XOR swizzle (row&7)
  __shared__ u16 Vs[4096];   // [64 d][64 kk], same swizzle
  __shared__ u16 Ps[8192];   // 8 waves x 16x64 strip, same swizzle

  int sr = tid >> 3, su = tid & 7;
  int kw = sr*64 + ((su ^ (sr&7)) << 3);
  const u16* kgb = K + ((size_t)bh*SS + sr)*HD + su*8;   // + kt*64*HD
  const u16* vgb = Vt + ((size_t)bh*HD + sr)*SS + su*8;  // + kt*64
  int pbase = w*1024;

  bf16x8 kreg = *(const bf16x8*)kgb;   // tile 0
  bf16x8 vreg = *(const bf16x8*)vgb;

  #pragma unroll 1
  for (int half = 0; half < 2; half++) {
    int qt2 = half ? (7 - ip) : ip;
    int last = 2*qt2 + 1;

    const u16* qbase = Q + ((size_t)bh*SS + qt2*128 + w*16 + lq)*HD;
    bf16x8 qa0 = *(const bf16x8*)(qbase + g*8);
    bf16x8 qa1 = *(const bf16x8*)(qbase + g*8 + 32);

    f32x4 o[4];
    #pragma unroll
    for (int nb=0;nb<4;nb++) o[nb] = (f32x4){0.f,0.f,0.f,0.f};
    float mrun[4], lrun[4];
    #pragma unroll
    for (int r=0;r<4;r++) { mrun[r] = -1e30f; lrun[r] = 0.f; }

    #pragma unroll 1
    for (int kt = 0; kt <= last; kt++) {
      __syncthreads();   // prior iter's LDS reads complete
      *(bf16x8*)&Ks[kw] = kreg;
      *(bf16x8*)&Vs[kw] = vreg;
      __syncthreads();
      if (kt < last) {   // prefetch next tile
        kreg = *(const bf16x8*)(kgb + (size_t)(kt+1)*64*HD);
        vreg = *(const bf16x8*)(vgb + (kt+1)*64);
      } else if (half == 0) {  // prefetch tile 0 for the second q-tile
        kreg = *(const bf16x8*)kgb;
        vreg = *(const bf16x8*)vgb;
      }
      if (kt*64 > qt2*128 + w*16 + 15) continue;

      // ---- S = Q K^T ----
      f32x4 s[4];
      #pragma unroll
      for (int nb=0;nb<4;nb++) s[nb] = (f32x4){0.f,0.f,0.f,0.f};
      #pragma unroll
      for (int ks=0; ks<2; ks++) {
        bf16x8 aq = ks ? qa1 : qa0;
        #pragma unroll
        for (int nb=0;nb<4;nb++) {
          bf16x8 kb = *(const bf16x8*)&Ks[(lq + 16*nb)*64 + (((g + 4*ks) ^ l7) << 3)];
          s[nb] = __builtin_amdgcn_mfma_f32_16x16x32_bf16(aq, kb, s[nb], 0, 0, 0);
        }
      }

      // ---- mask + online softmax ----
      bool diag = (kt*64 + 63 > qt2*128 + w*16);   // wave-uniform
      #pragma unroll
      for (int r=0;r<4;r++) {
        int qrow = qt2*128 + w*16 + g*4 + r;
        if (diag) {
          #pragma unroll
          for (int nb=0;nb<4;nb++)
            if (kt*64 + lq + 16*nb > qrow) s[nb][r] = -1e30f;
        }
        float rm = fmaxf(fmaxf(s[0][r], s[1][r]), fmaxf(s[2][r], s[3][r]));
        #pragma unroll
        for (int off=1; off<16; off<<=1) rm = fmaxf(rm, __shfl_xor(rm, off));
        float mnew = fmaxf(mrun[r], rm);
        float corr = __expf(mrun[r] - mnew);
        float psum = 0.f;
        int mrow = g*4 + r;
        #pragma unroll
        for (int nb=0;nb<4;nb++) {
          float p = __expf(s[nb][r] - mnew);
          psum += p;
          Ps[pbase + mrow*64 + ((((lq>>3) + 2*nb) ^ (mrow&7)) << 3) + l7] = f2bf(p);
        }
        #pragma unroll
        for (int off=1; off<16; off<<=1) psum += __shfl_xor(psum, off);
        lrun[r] = lrun[r]*corr + psum;
        mrun[r] = mnew;
        #pragma unroll
        for (int nb=0;nb<4;nb++) o[nb][r] *= corr;
      }

      // ---- O += P V ----
      #pragma unroll
      for (int ks=0; ks<2; ks++) {
        bf16x8 pa = *(const bf16x8*)&Ps[pbase + lq*64 + (((g + 4*ks) ^ l7) << 3)];
        #pragma unroll
        for (int nb=0;nb<4;nb++) {
          bf16x8 vb = *(const bf16x8*)&Vs[(lq + 16*nb)*64 + (((g + 4*ks) ^ l7) << 3)];
          o[nb] = __builtin_amdgcn_mfma_f32_16x16x32_bf16(pa, vb, o[nb], 0, 0, 0);
        }
      }
    }

    // ---- epilogue for this half ----
    #pragma unroll
    for (int r=0;r<4;r++) {
      float inv = 1.f / lrun[r];
      int qrow = qt2*128 + w*16 + g*4 + r;
      u16* cp = ctxb + ((size_t)b*SS + qrow)*DM + h*HD;
      #pragma unroll
      for (int nb=0;nb<4;nb++) cp[lq + 16*nb] = f2bf(o[nb][r] * inv);
    }
  }
}

// ---------------- LayerNorm in-place on x, dual write (f32 + bf16) ----------------
__global__ __launch_bounds__(256) void k_ln(
    float* __restrict__ x, const float* __restrict__ g,
    const float* __restrict__ b, u16* __restrict__ xb) {
  int row = blockIdx.x*4 + (threadIdx.x>>6);
  int lane = threadIdx.x & 63;
  float* xr = x + (size_t)row*DM;
  float vals[8]; float s1=0.f, s2=0.f;
  #pragma unroll
  for (int u=0;u<8;u++){ float vv = xr[lane + 64*u]; vals[u]=vv; s1+=vv; s2+=vv*vv; }
  #pragma unroll
  for (int off=1; off<64; off<<=1){ s1 += __shfl_xor(s1,off); s2 += __shfl_xor(s2,off); }
  float mu  = s1 * (1.0f/DM);
  float var = s2 * (1.0f/DM) - mu*mu;
  float inv = rsqrtf(var + 1e-5f);
  u16* xbr = xb + (size_t)row*DM;
  #pragma unroll
  for (int u=0;u<8;u++){
    int c = lane+64*u;
    float vv = (vals[u]-mu)*inv*g[c] + b[c];
    xr[c] = vv;
    xbr[c] = f2bf(vv);
  }
}

// ---------------- head: out = 1.5*tanh(x@w^T + b) ----------------
__global__ __launch_bounds__(256) void k_head(
    const float* __restrict__ x, const float* __restrict__ w,
    const float* __restrict__ b, float* __restrict__ out) {
  int row = blockIdx.x*4 + (threadIdx.x>>6);
  int lane = threadIdx.x & 63;
  const float* xr = x + (size_t)row*DM;
  float acc = 0.f;
  #pragma unroll
  for (int u=0;u<8;u++) acc += xr[lane+64*u]*w[lane+64*u];
  #pragma unroll
  for (int off=1; off<64; off<<=1) acc += __shfl_xor(acc,off);
  if (lane == 0) out[row] = 1.5f * tanhf(acc + b[0]);
}

extern "C" void kernel_launch(void* const* d_in, const int* in_sizes, int n_in,
                              void* d_out, int out_size, void* d_ws, size_t ws_size,
                              hipStream_t stream) {
  (void)in_sizes; (void)n_in; (void)out_size; (void)ws_size;
  const float* feat      = (const float*)d_in[0];
  const float* hist_w    = (const float*)d_in[1];
  const float* hist_b    = (const float*)d_in[2];
  const float* query_w   = (const float*)d_in[3];
  const float* query_b   = (const float*)d_in[4];
  const float* in_proj_w = (const float*)d_in[5];
  const float* in_proj_b = (const float*)d_in[6];
  const float* attn_w    = (const float*)d_in[7];
  const float* attn_b    = (const float*)d_in[8];
  const float* ln_g      = (const float*)d_in[9];
  const float* ln_b      = (const float*)d_in[10];
  const float* out_w     = (const float*)d_in[11];
  const float* out_b     = (const float*)d_in[12];
  float* out = (float*)d_out;

  float* ws = (float*)d_ws;
  const size_t P = (size_t)NROWS * DM;   // 8.39M elems
  float* x    = ws;                      // fp32 residual stream
  u16* xb     = (u16*)(ws + P);          // bf16 x
  u16* histb  = xb + P;                  // bf16 history (both layers)
  u16* ctxb   = histb + P;               // bf16 attention context
  u16* qbf    = ctxb + P;                // bf16 Q (b,h,s,d) prescaled
  u16* kbf    = qbf + P;                 // bf16 K (b,h,s,d)
  u16* vtb    = kbf + P;                 // bf16 V^T (b,h,d,s)
  u16* wipb   = vtb + P;                 // bf16 in_proj_w (2*1536*512)
  u16* wob    = wipb + (size_t)2*3*DM*DM;// bf16 attn_out_w (2*512*512)

  {
    int n4i = 2*3*DM*DM/4, n4o = 2*DM*DM/4;
    k_f2bf_v<<<(n4i+255)/256, 256, 0, stream>>>(in_proj_w, wipb, n4i);
    k_f2bf_v<<<(n4o+255)/256, 256, 0, stream>>>(attn_w, wob, n4o);
  }
  k_input_proj<<<NROWS/16, 256, 0, stream>>>(feat, hist_w, hist_b, query_w, query_b, histb, x, xb);

  for (int l = 0; l < 2; l++) {
    const u16* wq  = wipb + (size_t)l*3*DM*DM;
    const u16* wkv = wq + (size_t)DM*DM;
    const float* bq  = in_proj_b + (size_t)l*3*DM;
    const float* bkv = bq + DM;
    k_bgemm<1><<<dim3(4, 128), 256, 0, stream>>>(xb,    wq,  bq,  nullptr, qbf, nullptr);
    k_bgemm<2><<<dim3(8, 128), 256, 0, stream>>>(histb, wkv, bkv, nullptr, kbf, vtb);
    dim3 ga(4, BB*NH);
    k_attn_mfma<<<ga, 512, 0, stream>>>(qbf, kbf, vtb, ctxb);
    const u16* wo = wob + (size_t)l*DM*DM;
    const float* bo = attn_b + (size_t)l*DM;
    k_bgemm<3><<<dim3(4, 128), 256, 0, stream>>>(ctxb, wo, bo, x, nullptr, nullptr);
    k_ln<<<NROWS/4, 256, 0, stream>>>(x, ln_g + (size_t)l*DM, ln_b + (size_t)l*DM, xb);
  }
  k_head<<<NROWS/4, 256, 0, stream>>>(x, out_w, out_b, out);
}

// Round 14
// 409.099 us; speedup vs baseline: 8.2798x; 1.0088x over previous
//
#include <hip/hip_runtime.h>
#include <math.h>

#define DM 512
#define NH 8
#define HD 64
#define BB 16
#define SS 1024
#define NROWS (BB*SS)   // 16384
#define IND 16
#define KD 512

typedef unsigned short u16;
typedef __attribute__((ext_vector_type(8))) short bf16x8;
typedef __attribute__((ext_vector_type(4))) float f32x4;

// round-to-nearest-even f32 -> bf16 (finite inputs)
static __device__ __forceinline__ u16 f2bf(float f) {
  union { float f; unsigned int u; } v; v.f = f;
  unsigned int r = v.u + 0x7FFFu + ((v.u >> 16) & 1u);
  return (u16)(r >> 16);
}

static __device__ __forceinline__ float dot4(float4 a, float4 b) {
  return a.x*b.x + a.y*b.y + a.z*b.z + a.w*b.w;
}

// async global->LDS 16B DMA (lane l writes LDS base + l*16)
#define GLOAD_LDS16(gp, lp)                                                  \
  __builtin_amdgcn_global_load_lds(                                          \
      (const __attribute__((address_space(1))) void*)(gp),                   \
      (__attribute__((address_space(3))) void*)(lp), 16, 0, 0)

// ---------------- weight f32 -> bf16 (vectorized) ----------------
__global__ __launch_bounds__(256) void k_f2bf_v(const float* __restrict__ in,
                                                u16* __restrict__ out, int n4) {
  int i = blockIdx.x * 256 + threadIdx.x;
  if (i < n4) {
    float4 v = ((const float4*)in)[i];
    ushort4 p;
    p.x = f2bf(v.x); p.y = f2bf(v.y); p.z = f2bf(v.z); p.w = f2bf(v.w);
    ((ushort4*)out)[i] = p;
  }
}

// ---------------- input projections: hist(bf16), x(f32 + bf16) ----------------
__global__ __launch_bounds__(256) void k_input_proj(
    const float* __restrict__ feat, const float* __restrict__ hw, const float* __restrict__ hb,
    const float* __restrict__ qw, const float* __restrict__ qb,
    u16* __restrict__ histb, float* __restrict__ x, u16* __restrict__ xb) {
  int r0 = blockIdx.x * 16;
  int tid = threadIdx.x;
  int w = tid >> 6, lane = tid & 63;
  __shared__ float f[16][16];
  f[tid >> 4][tid & 15] = feat[(size_t)(r0 + (tid >> 4))*IND + (tid & 15)];
  __syncthreads();

  #pragma unroll
  for (int ch = 0; ch < 2; ch++) {
    int c0 = ch*256 + lane*4;
    // ---- hist projection ----
    {
      float4 wv[4][4];
      #pragma unroll
      for (int j=0;j<4;j++)
        #pragma unroll
        for (int kq=0;kq<4;kq++)
          wv[j][kq] = *(const float4*)(hw + (size_t)(c0+j)*IND + kq*4);
      float b0 = hb[c0], b1 = hb[c0+1], b2 = hb[c0+2], b3 = hb[c0+3];
      #pragma unroll
      for (int rr=0; rr<4; rr++) {
        int row = r0 + w*4 + rr;
        const float4* fr = (const float4*)f[w*4 + rr];
        float4 f0 = fr[0], f1 = fr[1], f2 = fr[2], f3 = fr[3];
        float v0 = b0 + dot4(wv[0][0],f0) + dot4(wv[0][1],f1) + dot4(wv[0][2],f2) + dot4(wv[0][3],f3);
        float v1 = b1 + dot4(wv[1][0],f0) + dot4(wv[1][1],f1) + dot4(wv[1][2],f2) + dot4(wv[1][3],f3);
        float v2 = b2 + dot4(wv[2][0],f0) + dot4(wv[2][1],f1) + dot4(wv[2][2],f2) + dot4(wv[2][3],f3);
        float v3 = b3 + dot4(wv[3][0],f0) + dot4(wv[3][1],f1) + dot4(wv[3][2],f2) + dot4(wv[3][3],f3);
        ushort4 hp; hp.x = f2bf(v0); hp.y = f2bf(v1); hp.z = f2bf(v2); hp.w = f2bf(v3);
        *(ushort4*)&histb[(size_t)row*DM + c0] = hp;
      }
    }
    // ---- query projection ----
    {
      float4 wv[4][4];
      #pragma unroll
      for (int j=0;j<4;j++)
        #pragma unroll
        for (int kq=0;kq<4;kq++)
          wv[j][kq] = *(const float4*)(qw + (size_t)(c0+j)*IND + kq*4);
      float b0 = qb[c0], b1 = qb[c0+1], b2 = qb[c0+2], b3 = qb[c0+3];
      #pragma unroll
      for (int rr=0; rr<4; rr++) {
        int row = r0 + w*4 + rr;
        const float4* fr = (const float4*)f[w*4 + rr];
        float4 f0 = fr[0], f1 = fr[1], f2 = fr[2], f3 = fr[3];
        float v0 = b0 + dot4(wv[0][0],f0) + dot4(wv[0][1],f1) + dot4(wv[0][2],f2) + dot4(wv[0][3],f3);
        float v1 = b1 + dot4(wv[1][0],f0) + dot4(wv[1][1],f1) + dot4(wv[1][2],f2) + dot4(wv[1][3],f3);
        float v2 = b2 + dot4(wv[2][0],f0) + dot4(wv[2][1],f1) + dot4(wv[2][2],f2) + dot4(wv[2][3],f3);
        float v3 = b3 + dot4(wv[3][0],f0) + dot4(wv[3][1],f1) + dot4(wv[3][2],f2) + dot4(wv[3][3],f3);
        float4 xv; xv.x = v0; xv.y = v1; xv.z = v2; xv.w = v3;
        *(float4*)&x[(size_t)row*DM + c0] = xv;
        ushort4 xp; xp.x = f2bf(v0); xp.y = f2bf(v1); xp.z = f2bf(v2); xp.w = f2bf(v3);
        *(ushort4*)&xb[(size_t)row*DM + c0] = xp;
      }
    }
  }
}

// ---------------- bf16 MFMA GEMM: C = A[M,512] @ W[N,512]^T + bias ----------------
// 128x128 tile, 4 waves, BK=64, double-buffered LDS with COUNTED vmcnt pipeline:
// per K-step: issue next tile's 8 DMAs -> s_waitcnt vmcnt(8) (waits only for the
// PREVIOUS tile's DMAs, FIFO) -> raw s_barrier -> 32 MFMAs -> raw s_barrier.
// No vmcnt(0) drain in the main loop (the R11 __syncthreads version drained the
// just-issued prefetch every step - full latency exposed).
template<int EPI>
__global__ __launch_bounds__(256) void k_bgemm(
    const u16* __restrict__ A, const u16* __restrict__ Wb,
    const float* __restrict__ bias,
    float* __restrict__ Cf, u16* __restrict__ C0h, u16* __restrict__ C1h) {
  __shared__ u16 As[2][128*64];
  __shared__ u16 Bs[2][128*64];
  int bm = blockIdx.y * 128, bn = blockIdx.x * 128;
  int tid = threadIdx.x;
  int wv = tid >> 6, lane = tid & 63;
  int wm = (wv >> 1) * 64, wn = (wv & 1) * 64;
  int lq = lane & 15, g = lane >> 4, l7 = lq & 7;

  // DMA staging mapping (linear dest + inverse-swizzled source, rule #21)
  int rsub = lane >> 3;            // 0..7 (row within 8-row stripe)
  int sug  = (lane & 7) ^ rsub;    // inverse-swizzled source 16B-unit
  const u16* Ag = A  + (size_t)(bm + wv*32 + rsub)*KD + sug*8;
  const u16* Bg = Wb + (size_t)(bn + wv*32 + rsub)*KD + sug*8;

  f32x4 acc[4][4];
  #pragma unroll
  for (int mf=0;mf<4;mf++)
    #pragma unroll
    for (int nf=0;nf<4;nf++) acc[mf][nf] = (f32x4){0.f,0.f,0.f,0.f};

  // prologue: stage tile 0 into buffer 0, full drain
  #pragma unroll
  for (int j=0;j<4;j++) {
    GLOAD_LDS16(Ag + (size_t)j*8*KD, &As[0][(wv*32 + j*8)*64]);
    GLOAD_LDS16(Bg + (size_t)j*8*KD, &Bs[0][(wv*32 + j*8)*64]);
  }
  asm volatile("s_waitcnt vmcnt(0)" ::: "memory");
  __builtin_amdgcn_sched_barrier(0);
  __builtin_amdgcn_s_barrier();

  #pragma unroll 1
  for (int t = 0; t < 8; t++) {
    int cur = t & 1;
    if (t < 7) {     // issue next tile's 8 DMAs into the other buffer
      int nxt = cur ^ 1;
      int k0n = (t+1)*64;
      #pragma unroll
      for (int j=0;j<4;j++) {
        GLOAD_LDS16(Ag + (size_t)j*8*KD + k0n, &As[nxt][(wv*32 + j*8)*64]);
        GLOAD_LDS16(Bg + (size_t)j*8*KD + k0n, &Bs[nxt][(wv*32 + j*8)*64]);
      }
      // wait until only the 8 just-issued remain -> tile t's DMAs complete
      asm volatile("s_waitcnt vmcnt(8)" ::: "memory");
    } else {
      asm volatile("s_waitcnt vmcnt(0)" ::: "memory");
    }
    __builtin_amdgcn_sched_barrier(0);
    __builtin_amdgcn_s_barrier();   // cross-wave: every wave's tile-t data resident
    __builtin_amdgcn_sched_barrier(0);

    const u16* Ac = As[cur];
    const u16* Bc = Bs[cur];
    #pragma unroll
    for (int ks=0; ks<2; ks++) {
      int un = ((g + 4*ks) ^ l7) << 3;
      bf16x8 af[4], bfr[4];
      #pragma unroll
      for (int mf=0;mf<4;mf++) af[mf]  = *(const bf16x8*)&Ac[(wm + mf*16 + lq)*64 + un];
      #pragma unroll
      for (int nf=0;nf<4;nf++) bfr[nf] = *(const bf16x8*)&Bc[(wn + nf*16 + lq)*64 + un];
      #pragma unroll
      for (int mf=0;mf<4;mf++)
        #pragma unroll
        for (int nf=0;nf<4;nf++)
          acc[mf][nf] = __builtin_amdgcn_mfma_f32_16x16x32_bf16(af[mf], bfr[nf], acc[mf][nf], 0, 0, 0);
    }
    __builtin_amdgcn_s_barrier();   // all waves done reading cur before t+1 DMAs into it
  }

  float fb[4];
  #pragma unroll
  for (int nf=0;nf<4;nf++) fb[nf] = bias[bn + wn + nf*16 + lq];
  int m0 = bm + wm + g*4;
  int n0 = bn + wn + lq;

  if (EPI == 1 || (EPI == 2 && bn < 512)) {
    const float sc = (EPI == 1) ? 0.125f : 1.0f;
    #pragma unroll
    for (int mf=0;mf<4;mf++) {
      int mb = m0 + mf*16;
      int b = mb >> 10, s = mb & 1023;
      #pragma unroll
      for (int nf=0;nf<4;nf++) {
        int n = n0 + nf*16;
        int h = (n >> 6) & 7, d = n & 63;
        u16* dst = C0h + (((size_t)(b*NH + h))*SS + s)*HD + d;
        #pragma unroll
        for (int r=0;r<4;r++) dst[r*HD] = f2bf((acc[mf][nf][r] + fb[nf]) * sc);
      }
    }
  } else if (EPI == 2) {
    #pragma unroll
    for (int mf=0;mf<4;mf++) {
      int mb = m0 + mf*16;
      int b = mb >> 10, s = mb & 1023;
      #pragma unroll
      for (int nf=0;nf<4;nf++) {
        int n = n0 + nf*16 - 512;
        int h = n >> 6, d = n & 63;
        ushort4 pk;
        pk.x = f2bf(acc[mf][nf][0] + fb[nf]);
        pk.y = f2bf(acc[mf][nf][1] + fb[nf]);
        pk.z = f2bf(acc[mf][nf][2] + fb[nf]);
        pk.w = f2bf(acc[mf][nf][3] + fb[nf]);
        *(ushort4*)&C1h[(((size_t)(b*NH + h))*HD + d)*SS + s] = pk;
      }
    }
  } else {
    #pragma unroll
    for (int mf=0;mf<4;mf++) {
      #pragma unroll
      for (int r=0;r<4;r++) {
        int m = m0 + mf*16 + r;
        #pragma unroll
        for (int nf=0;nf<4;nf++) {
          int n = n0 + nf*16;
          Cf[(size_t)m*DM + n] = acc[mf][nf][r] + fb[nf] + Cf[(size_t)m*DM + n];
        }
      }
    }
  }
}

// ---------------- flash attention, bf16 MFMA, causal; 512 thr, paired q-tiles ----------------
// blockIdx.x = i (0..3): processes 128-row q-tile i then q-tile 7-i (18 K-iters uniform).
__global__ __launch_bounds__(512) void k_attn_mfma(
    const u16* __restrict__ Q, const u16* __restrict__ K,
    const u16* __restrict__ Vt, u16* __restrict__ ctxb) {
  int ip = blockIdx.x;          // 0..3 pair index
  int bh = blockIdx.y;          // 0..127
  int b = bh >> 3, h = bh & 7;
  int tid = threadIdx.x;
  int w = tid >> 6, lane = tid & 63;
  int lq = lane & 15, g = lane >> 4;
  int l7 = lq & 7;

  __shared__ u16 Ks[4096];   // [64 kk][64 d], 16B-unit XOR swizzle (row&7)
  __shared__ u16 Vs[4096];   // [64 d][64 kk], same swizzle
  __shared__ u16 Ps[8192];   // 8 waves x 16x64 strip, same swizzle

  int sr = tid >> 3, su = tid & 7;
  int kw = sr*64 + ((su ^ (sr&7)) << 3);
  const u16* kgb = K + ((size_t)bh*SS + sr)*HD + su*8;   // + kt*64*HD
  const u16* vgb = Vt + ((size_t)bh*HD + sr)*SS + su*8;  // + kt*64
  int pbase = w*1024;

  bf16x8 kreg = *(const bf16x8*)kgb;   // tile 0
  bf16x8 vreg = *(const bf16x8*)vgb;

  #pragma unroll 1
  for (int half = 0; half < 2; half++) {
    int qt2 = half ? (7 - ip) : ip;
    int last = 2*qt2 + 1;

    const u16* qbase = Q + ((size_t)bh*SS + qt2*128 + w*16 + lq)*HD;
    bf16x8 qa0 = *(const bf16x8*)(qbase + g*8);
    bf16x8 qa1 = *(const bf16x8*)(qbase + g*8 + 32);

    f32x4 o[4];
    #pragma unroll
    for (int nb=0;nb<4;nb++) o[nb] = (f32x4){0.f,0.f,0.f,0.f};
    float mrun[4], lrun[4];
    #pragma unroll
    for (int r=0;r<4;r++) { mrun[r] = -1e30f; lrun[r] = 0.f; }

    #pragma unroll 1
    for (int kt = 0; kt <= last; kt++) {
      __syncthreads();   // prior iter's LDS reads complete
      *(bf16x8*)&Ks[kw] = kreg;
      *(bf16x8*)&Vs[kw] = vreg;
      __syncthreads();
      if (kt < last) {   // prefetch next tile
        kreg = *(const bf16x8*)(kgb + (size_t)(kt+1)*64*HD);
        vreg = *(const bf16x8*)(vgb + (kt+1)*64);
      } else if (half == 0) {  // prefetch tile 0 for the second q-tile
        kreg = *(const bf16x8*)kgb;
        vreg = *(const bf16x8*)vgb;
      }
      if (kt*64 > qt2*128 + w*16 + 15) continue;

      // ---- S = Q K^T ----
      f32x4 s[4];
      #pragma unroll
      for (int nb=0;nb<4;nb++) s[nb] = (f32x4){0.f,0.f,0.f,0.f};
      #pragma unroll
      for (int ks=0; ks<2; ks++) {
        bf16x8 aq = ks ? qa1 : qa0;
        #pragma unroll
        for (int nb=0;nb<4;nb++) {
          bf16x8 kb = *(const bf16x8*)&Ks[(lq + 16*nb)*64 + (((g + 4*ks) ^ l7) << 3)];
          s[nb] = __builtin_amdgcn_mfma_f32_16x16x32_bf16(aq, kb, s[nb], 0, 0, 0);
        }
      }

      // ---- mask + online softmax ----
      bool diag = (kt*64 + 63 > qt2*128 + w*16);   // wave-uniform
      #pragma unroll
      for (int r=0;r<4;r++) {
        int qrow = qt2*128 + w*16 + g*4 + r;
        if (diag) {
          #pragma unroll
          for (int nb=0;nb<4;nb++)
            if (kt*64 + lq + 16*nb > qrow) s[nb][r] = -1e30f;
        }
        float rm = fmaxf(fmaxf(s[0][r], s[1][r]), fmaxf(s[2][r], s[3][r]));
        #pragma unroll
        for (int off=1; off<16; off<<=1) rm = fmaxf(rm, __shfl_xor(rm, off));
        float mnew = fmaxf(mrun[r], rm);
        float corr = __expf(mrun[r] - mnew);
        float psum = 0.f;
        int mrow = g*4 + r;
        #pragma unroll
        for (int nb=0;nb<4;nb++) {
          float p = __expf(s[nb][r] - mnew);
          psum += p;
          Ps[pbase + mrow*64 + ((((lq>>3) + 2*nb) ^ (mrow&7)) << 3) + l7] = f2bf(p);
        }
        #pragma unroll
        for (int off=1; off<16; off<<=1) psum += __shfl_xor(psum, off);
        lrun[r] = lrun[r]*corr + psum;
        mrun[r] = mnew;
        #pragma unroll
        for (int nb=0;nb<4;nb++) o[nb][r] *= corr;
      }

      // ---- O += P V ----
      #pragma unroll
      for (int ks=0; ks<2; ks++) {
        bf16x8 pa = *(const bf16x8*)&Ps[pbase + lq*64 + (((g + 4*ks) ^ l7) << 3)];
        #pragma unroll
        for (int nb=0;nb<4;nb++) {
          bf16x8 vb = *(const bf16x8*)&Vs[(lq + 16*nb)*64 + (((g + 4*ks) ^ l7) << 3)];
          o[nb] = __builtin_amdgcn_mfma_f32_16x16x32_bf16(pa, vb, o[nb], 0, 0, 0);
        }
      }
    }

    // ---- epilogue for this half ----
    #pragma unroll
    for (int r=0;r<4;r++) {
      float inv = 1.f / lrun[r];
      int qrow = qt2*128 + w*16 + g*4 + r;
      u16* cp = ctxb + ((size_t)b*SS + qrow)*DM + h*HD;
      #pragma unroll
      for (int nb=0;nb<4;nb++) cp[lq + 16*nb] = f2bf(o[nb][r] * inv);
    }
  }
}

// ---------------- LayerNorm in-place on x, dual write (f32 + bf16) ----------------
__global__ __launch_bounds__(256) void k_ln(
    float* __restrict__ x, const float* __restrict__ g,
    const float* __restrict__ b, u16* __restrict__ xb) {
  int row = blockIdx.x*4 + (threadIdx.x>>6);
  int lane = threadIdx.x & 63;
  float* xr = x + (size_t)row*DM;
  float vals[8]; float s1=0.f, s2=0.f;
  #pragma unroll
  for (int u=0;u<8;u++){ float vv = xr[lane + 64*u]; vals[u]=vv; s1+=vv; s2+=vv*vv; }
  #pragma unroll
  for (int off=1; off<64; off<<=1){ s1 += __shfl_xor(s1,off); s2 += __shfl_xor(s2,off); }
  float mu  = s1 * (1.0f/DM);
  float var = s2 * (1.0f/DM) - mu*mu;
  float inv = rsqrtf(var + 1e-5f);
  u16* xbr = xb + (size_t)row*DM;
  #pragma unroll
  for (int u=0;u<8;u++){
    int c = lane+64*u;
    float vv = (vals[u]-mu)*inv*g[c] + b[c];
    xr[c] = vv;
    xbr[c] = f2bf(vv);
  }
}

// ---------------- head: out = 1.5*tanh(x@w^T + b) ----------------
__global__ __launch_bounds__(256) void k_head(
    const float* __restrict__ x, const float* __restrict__ w,
    const float* __restrict__ b, float* __restrict__ out) {
  int row = blockIdx.x*4 + (threadIdx.x>>6);
  int lane = threadIdx.x & 63;
  const float* xr = x + (size_t)row*DM;
  float acc = 0.f;
  #pragma unroll
  for (int u=0;u<8;u++) acc += xr[lane+64*u]*w[lane+64*u];
  #pragma unroll
  for (int off=1; off<64; off<<=1) acc += __shfl_xor(acc,off);
  if (lane == 0) out[row] = 1.5f * tanhf(acc + b[0]);
}

extern "C" void kernel_launch(void* const* d_in, const int* in_sizes, int n_in,
                              void* d_out, int out_size, void* d_ws, size_t ws_size,
                              hipStream_t stream) {
  (void)in_sizes; (void)n_in; (void)out_size; (void)ws_size;
  const float* feat      = (const float*)d_in[0];
  const float* hist_w    = (const float*)d_in[1];
  const float* hist_b    = (const float*)d_in[2];
  const float* query_w   = (const float*)d_in[3];
  const float* query_b   = (const float*)d_in[4];
  const float* in_proj_w = (const float*)d_in[5];
  const float* in_proj_b = (const float*)d_in[6];
  const float* attn_w    = (const float*)d_in[7];
  const float* attn_b    = (const float*)d_in[8];
  const float* ln_g      = (const float*)d_in[9];
  const float* ln_b      = (const float*)d_in[10];
  const float* out_w     = (const float*)d_in[11];
  const float* out_b     = (const float*)d_in[12];
  float* out = (float*)d_out;

  float* ws = (float*)d_ws;
  const size_t P = (size_t)NROWS * DM;   // 8.39M elems
  float* x    = ws;                      // fp32 residual stream
  u16* xb     = (u16*)(ws + P);          // bf16 x
  u16* histb  = xb + P;                  // bf16 history (both layers)
  u16* ctxb   = histb + P;               // bf16 attention context
  u16* qbf    = ctxb + P;                // bf16 Q (b,h,s,d) prescaled
  u16* kbf    = qbf + P;                 // bf16 K (b,h,s,d)
  u16* vtb    = kbf + P;                 // bf16 V^T (b,h,d,s)
  u16* wipb   = vtb + P;                 // bf16 in_proj_w (2*1536*512)
  u16* wob    = wipb + (size_t)2*3*DM*DM;// bf16 attn_out_w (2*512*512)

  {
    int n4i = 2*3*DM*DM/4, n4o = 2*DM*DM/4;
    k_f2bf_v<<<(n4i+255)/256, 256, 0, stream>>>(in_proj_w, wipb, n4i);
    k_f2bf_v<<<(n4o+255)/256, 256, 0, stream>>>(attn_w, wob, n4o);
  }
  k_input_proj<<<NROWS/16, 256, 0, stream>>>(feat, hist_w, hist_b, query_w, query_b, histb, x, xb);

  for (int l = 0; l < 2; l++) {
    const u16* wq  = wipb + (size_t)l*3*DM*DM;
    const u16* wkv = wq + (size_t)DM*DM;
    const float* bq  = in_proj_b + (size_t)l*3*DM;
    const float* bkv = bq + DM;
    k_bgemm<1><<<dim3(4, 128), 256, 0, stream>>>(xb,    wq,  bq,  nullptr, qbf, nullptr);
    k_bgemm<2><<<dim3(8, 128), 256, 0, stream>>>(histb, wkv, bkv, nullptr, kbf, vtb);
    dim3 ga(4, BB*NH);
    k_attn_mfma<<<ga, 512, 0, stream>>>(qbf, kbf, vtb, ctxb);
    const u16* wo = wob + (size_t)l*DM*DM;
    const float* bo = attn_b + (size_t)l*DM;
    k_bgemm<3><<<dim3(4, 128), 256, 0, stream>>>(ctxb, wo, bo, x, nullptr, nullptr);
    k_ln<<<NROWS/4, 256, 0, stream>>>(x, ln_g + (size_t)l*DM, ln_b + (size_t)l*DM, xb);
  }
  k_head<<<NROWS/4, 256, 0, stream>>>(x, out_w, out_b, out);
}

// Round 15
// 397.514 us; speedup vs baseline: 8.5212x; 1.0291x over previous
//
#include <hip/hip_runtime.h>
#include <math.h>

#define DM 512
#define NH 8
#define HD 64
#define BB 16
#define SS 1024
#define NROWS (BB*SS)   // 16384
#define IND 16
#define KD 512

typedef unsigned short u16;
typedef __attribute__((ext_vector_type(8))) short bf16x8;
typedef __attribute__((ext_vector_type(4))) float f32x4;

// round-to-nearest-even f32 -> bf16 (finite inputs)
static __device__ __forceinline__ u16 f2bf(float f) {
  union { float f; unsigned int u; } v; v.f = f;
  unsigned int r = v.u + 0x7FFFu + ((v.u >> 16) & 1u);
  return (u16)(r >> 16);
}

static __device__ __forceinline__ float dot4(float4 a, float4 b) {
  return a.x*b.x + a.y*b.y + a.z*b.z + a.w*b.w;
}

// async global->LDS 16B DMA (lane l writes LDS base + l*16)
#define GLOAD_LDS16(gp, lp)                                                  \
  __builtin_amdgcn_global_load_lds(                                          \
      (const __attribute__((address_space(1))) void*)(gp),                   \
      (__attribute__((address_space(3))) void*)(lp), 16, 0, 0)

// ---------------- weight f32 -> bf16 (vectorized) ----------------
__global__ __launch_bounds__(256) void k_f2bf_v(const float* __restrict__ in,
                                                u16* __restrict__ out, int n4) {
  int i = blockIdx.x * 256 + threadIdx.x;
  if (i < n4) {
    float4 v = ((const float4*)in)[i];
    ushort4 p;
    p.x = f2bf(v.x); p.y = f2bf(v.y); p.z = f2bf(v.z); p.w = f2bf(v.w);
    ((ushort4*)out)[i] = p;
  }
}

// ---------------- input projections: hist(bf16), x(f32 + bf16) ----------------
__global__ __launch_bounds__(256) void k_input_proj(
    const float* __restrict__ feat, const float* __restrict__ hw, const float* __restrict__ hb,
    const float* __restrict__ qw, const float* __restrict__ qb,
    u16* __restrict__ histb, float* __restrict__ x, u16* __restrict__ xb) {
  int r0 = blockIdx.x * 16;
  int tid = threadIdx.x;
  int w = tid >> 6, lane = tid & 63;
  __shared__ float f[16][16];
  f[tid >> 4][tid & 15] = feat[(size_t)(r0 + (tid >> 4))*IND + (tid & 15)];
  __syncthreads();

  #pragma unroll
  for (int ch = 0; ch < 2; ch++) {
    int c0 = ch*256 + lane*4;
    // ---- hist projection ----
    {
      float4 wv[4][4];
      #pragma unroll
      for (int j=0;j<4;j++)
        #pragma unroll
        for (int kq=0;kq<4;kq++)
          wv[j][kq] = *(const float4*)(hw + (size_t)(c0+j)*IND + kq*4);
      float b0 = hb[c0], b1 = hb[c0+1], b2 = hb[c0+2], b3 = hb[c0+3];
      #pragma unroll
      for (int rr=0; rr<4; rr++) {
        int row = r0 + w*4 + rr;
        const float4* fr = (const float4*)f[w*4 + rr];
        float4 f0 = fr[0], f1 = fr[1], f2 = fr[2], f3 = fr[3];
        float v0 = b0 + dot4(wv[0][0],f0) + dot4(wv[0][1],f1) + dot4(wv[0][2],f2) + dot4(wv[0][3],f3);
        float v1 = b1 + dot4(wv[1][0],f0) + dot4(wv[1][1],f1) + dot4(wv[1][2],f2) + dot4(wv[1][3],f3);
        float v2 = b2 + dot4(wv[2][0],f0) + dot4(wv[2][1],f1) + dot4(wv[2][2],f2) + dot4(wv[2][3],f3);
        float v3 = b3 + dot4(wv[3][0],f0) + dot4(wv[3][1],f1) + dot4(wv[3][2],f2) + dot4(wv[3][3],f3);
        ushort4 hp; hp.x = f2bf(v0); hp.y = f2bf(v1); hp.z = f2bf(v2); hp.w = f2bf(v3);
        *(ushort4*)&histb[(size_t)row*DM + c0] = hp;
      }
    }
    // ---- query projection ----
    {
      float4 wv[4][4];
      #pragma unroll
      for (int j=0;j<4;j++)
        #pragma unroll
        for (int kq=0;kq<4;kq++)
          wv[j][kq] = *(const float4*)(qw + (size_t)(c0+j)*IND + kq*4);
      float b0 = qb[c0], b1 = qb[c0+1], b2 = qb[c0+2], b3 = qb[c0+3];
      #pragma unroll
      for (int rr=0; rr<4; rr++) {
        int row = r0 + w*4 + rr;
        const float4* fr = (const float4*)f[w*4 + rr];
        float4 f0 = fr[0], f1 = fr[1], f2 = fr[2], f3 = fr[3];
        float v0 = b0 + dot4(wv[0][0],f0) + dot4(wv[0][1],f1) + dot4(wv[0][2],f2) + dot4(wv[0][3],f3);
        float v1 = b1 + dot4(wv[1][0],f0) + dot4(wv[1][1],f1) + dot4(wv[1][2],f2) + dot4(wv[1][3],f3);
        float v2 = b2 + dot4(wv[2][0],f0) + dot4(wv[2][1],f1) + dot4(wv[2][2],f2) + dot4(wv[2][3],f3);
        float v3 = b3 + dot4(wv[3][0],f0) + dot4(wv[3][1],f1) + dot4(wv[3][2],f2) + dot4(wv[3][3],f3);
        float4 xv; xv.x = v0; xv.y = v1; xv.z = v2; xv.w = v3;
        *(float4*)&x[(size_t)row*DM + c0] = xv;
        ushort4 xp; xp.x = f2bf(v0); xp.y = f2bf(v1); xp.z = f2bf(v2); xp.w = f2bf(v3);
        *(ushort4*)&xb[(size_t)row*DM + c0] = xp;
      }
    }
  }
}

// ---------------- merged QKV bf16 MFMA GEMM ----------------
// 1536 blocks (XCD-chunked). Per block: 128x128 tile, 4 waves, BK=64,
// single-buffer 32KB LDS, m97 2-barrier loop with global_load_lds w16.
// Work id w: gx = w%12 (gx<4: Q from xb; else K/V from histb), gy = w/12 (bm).
__global__ __launch_bounds__(256) void k_bgemm_qkv(
    const u16* __restrict__ xb, const u16* __restrict__ histb,
    const u16* __restrict__ wq, const u16* __restrict__ wkv,
    const float* __restrict__ bq, const float* __restrict__ bkv,
    u16* __restrict__ qbf, u16* __restrict__ kbf, u16* __restrict__ vtb) {
  __shared__ u16 As[128*64];
  __shared__ u16 Bs[128*64];
  int bid = blockIdx.x;
  int wid = (bid & 7)*192 + (bid >> 3);   // XCD-chunked bijection (1536 = 8*192)
  int gx = wid % 12, gy = wid / 12;
  int bm = gy * 128;
  bool isQ = gx < 4;
  int bn = isQ ? gx*128 : (gx-4)*128;     // col-block within respective N
  const u16* A   = isQ ? xb : histb;
  const u16* Wbp = (isQ ? wq : wkv) + (size_t)bn*KD;
  const float* bias = (isQ ? bq : bkv) + bn;

  int tid = threadIdx.x;
  int wv = tid >> 6, lane = tid & 63;
  int wm = (wv >> 1) * 64, wn = (wv & 1) * 64;
  int lq = lane & 15, g = lane >> 4, l7 = lq & 7;

  // DMA staging (linear dest + inverse-swizzled source)
  int rsub = lane >> 3;
  int sug  = (lane & 7) ^ rsub;
  const u16* Ag = A   + (size_t)(bm + wv*32 + rsub)*KD + sug*8;
  const u16* Bg = Wbp + (size_t)(wv*32 + rsub)*KD + sug*8;

  f32x4 acc[4][4];
  #pragma unroll
  for (int mf=0;mf<4;mf++)
    #pragma unroll
    for (int nf=0;nf<4;nf++) acc[mf][nf] = (f32x4){0.f,0.f,0.f,0.f};

  #pragma unroll 1
  for (int t = 0; t < 8; t++) {
    int k0 = t*64;
    #pragma unroll
    for (int j=0;j<4;j++) {
      GLOAD_LDS16(Ag + (size_t)j*8*KD + k0, &As[(wv*32 + j*8)*64]);
      GLOAD_LDS16(Bg + (size_t)j*8*KD + k0, &Bs[(wv*32 + j*8)*64]);
    }
    __syncthreads();   // vmcnt(0) drain: tile resident
    #pragma unroll
    for (int ks=0; ks<2; ks++) {
      int un = ((g + 4*ks) ^ l7) << 3;
      bf16x8 af[4], bfr[4];
      #pragma unroll
      for (int mf=0;mf<4;mf++) af[mf]  = *(const bf16x8*)&As[(wm + mf*16 + lq)*64 + un];
      #pragma unroll
      for (int nf=0;nf<4;nf++) bfr[nf] = *(const bf16x8*)&Bs[(wn + nf*16 + lq)*64 + un];
      #pragma unroll
      for (int mf=0;mf<4;mf++)
        #pragma unroll
        for (int nf=0;nf<4;nf++)
          acc[mf][nf] = __builtin_amdgcn_mfma_f32_16x16x32_bf16(af[mf], bfr[nf], acc[mf][nf], 0, 0, 0);
    }
    __syncthreads();   // all waves done reading before next tile overwrites
  }

  float fb[4];
  #pragma unroll
  for (int nf=0;nf<4;nf++) fb[nf] = bias[wn + nf*16 + lq];
  int m0 = bm + wm + g*4;
  int n0 = bn + wn + lq;

  if (isQ || bn < 512) {
    const float sc = isQ ? 0.125f : 1.0f;
    u16* dstb = isQ ? qbf : kbf;
    #pragma unroll
    for (int mf=0;mf<4;mf++) {
      int mb = m0 + mf*16;
      int b = mb >> 10, s = mb & 1023;
      #pragma unroll
      for (int nf=0;nf<4;nf++) {
        int n = n0 + nf*16;
        int h = (n >> 6) & 7, d = n & 63;
        u16* dst = dstb + (((size_t)(b*NH + h))*SS + s)*HD + d;
        #pragma unroll
        for (int r=0;r<4;r++) dst[r*HD] = f2bf((acc[mf][nf][r] + fb[nf]) * sc);
      }
    }
  } else {   // V^T
    #pragma unroll
    for (int mf=0;mf<4;mf++) {
      int mb = m0 + mf*16;
      int b = mb >> 10, s = mb & 1023;
      #pragma unroll
      for (int nf=0;nf<4;nf++) {
        int n = n0 + nf*16 - 512;
        int h = n >> 6, d = n & 63;
        ushort4 pk;
        pk.x = f2bf(acc[mf][nf][0] + fb[nf]);
        pk.y = f2bf(acc[mf][nf][1] + fb[nf]);
        pk.z = f2bf(acc[mf][nf][2] + fb[nf]);
        pk.w = f2bf(acc[mf][nf][3] + fb[nf]);
        *(ushort4*)&vtb[(((size_t)(b*NH + h))*HD + d)*SS + s] = pk;
      }
    }
  }
}

// ---------------- out-proj bf16 MFMA GEMM, in-place residual ----------------
// 512 blocks (XCD-chunked), same single-buffer structure; Cf += acc + bias.
__global__ __launch_bounds__(256) void k_bgemm_o(
    const u16* __restrict__ A, const u16* __restrict__ Wb,
    const float* __restrict__ bias, float* __restrict__ Cf) {
  __shared__ u16 As[128*64];
  __shared__ u16 Bs[128*64];
  int bid = blockIdx.x;
  int wid = (bid & 7)*64 + (bid >> 3);    // 512 = 8*64
  int gx = wid & 3, gy = wid >> 2;
  int bm = gy * 128, bn = gx * 128;

  int tid = threadIdx.x;
  int wv = tid >> 6, lane = tid & 63;
  int wm = (wv >> 1) * 64, wn = (wv & 1) * 64;
  int lq = lane & 15, g = lane >> 4, l7 = lq & 7;

  int rsub = lane >> 3;
  int sug  = (lane & 7) ^ rsub;
  const u16* Ag = A  + (size_t)(bm + wv*32 + rsub)*KD + sug*8;
  const u16* Bg = Wb + (size_t)(bn + wv*32 + rsub)*KD + sug*8;

  f32x4 acc[4][4];
  #pragma unroll
  for (int mf=0;mf<4;mf++)
    #pragma unroll
    for (int nf=0;nf<4;nf++) acc[mf][nf] = (f32x4){0.f,0.f,0.f,0.f};

  #pragma unroll 1
  for (int t = 0; t < 8; t++) {
    int k0 = t*64;
    #pragma unroll
    for (int j=0;j<4;j++) {
      GLOAD_LDS16(Ag + (size_t)j*8*KD + k0, &As[(wv*32 + j*8)*64]);
      GLOAD_LDS16(Bg + (size_t)j*8*KD + k0, &Bs[(wv*32 + j*8)*64]);
    }
    __syncthreads();
    #pragma unroll
    for (int ks=0; ks<2; ks++) {
      int un = ((g + 4*ks) ^ l7) << 3;
      bf16x8 af[4], bfr[4];
      #pragma unroll
      for (int mf=0;mf<4;mf++) af[mf]  = *(const bf16x8*)&As[(wm + mf*16 + lq)*64 + un];
      #pragma unroll
      for (int nf=0;nf<4;nf++) bfr[nf] = *(const bf16x8*)&Bs[(wn + nf*16 + lq)*64 + un];
      #pragma unroll
      for (int mf=0;mf<4;mf++)
        #pragma unroll
        for (int nf=0;nf<4;nf++)
          acc[mf][nf] = __builtin_amdgcn_mfma_f32_16x16x32_bf16(af[mf], bfr[nf], acc[mf][nf], 0, 0, 0);
    }
    __syncthreads();
  }

  float fb[4];
  #pragma unroll
  for (int nf=0;nf<4;nf++) fb[nf] = bias[bn + wn + nf*16 + lq];
  int m0 = bm + wm + g*4;
  int n0 = bn + wn + lq;
  #pragma unroll
  for (int mf=0;mf<4;mf++) {
    #pragma unroll
    for (int r=0;r<4;r++) {
      int m = m0 + mf*16 + r;
      #pragma unroll
      for (int nf=0;nf<4;nf++) {
        int n = n0 + nf*16;
        Cf[(size_t)m*DM + n] = acc[mf][nf][r] + fb[nf] + Cf[(size_t)m*DM + n];
      }
    }
  }
}

// ---------------- flash attention, bf16 MFMA, causal; 512 thr, paired q-tiles ----------------
__global__ __launch_bounds__(512) void k_attn_mfma(
    const u16* __restrict__ Q, const u16* __restrict__ K,
    const u16* __restrict__ Vt, u16* __restrict__ ctxb) {
  int ip = blockIdx.x;          // 0..3 pair index
  int bh = blockIdx.y;          // 0..127
  int b = bh >> 3, h = bh & 7;
  int tid = threadIdx.x;
  int w = tid >> 6, lane = tid & 63;
  int lq = lane & 15, g = lane >> 4;
  int l7 = lq & 7;

  __shared__ u16 Ks[4096];   // [64 kk][64 d], 16B-unit XOR swizzle (row&7)
  __shared__ u16 Vs[4096];   // [64 d][64 kk], same swizzle
  __shared__ u16 Ps[8192];   // 8 waves x 16x64 strip, same swizzle

  int sr = tid >> 3, su = tid & 7;
  int kw = sr*64 + ((su ^ (sr&7)) << 3);
  const u16* kgb = K + ((size_t)bh*SS + sr)*HD + su*8;   // + kt*64*HD
  const u16* vgb = Vt + ((size_t)bh*HD + sr)*SS + su*8;  // + kt*64
  int pbase = w*1024;

  bf16x8 kreg = *(const bf16x8*)kgb;   // tile 0
  bf16x8 vreg = *(const bf16x8*)vgb;

  #pragma unroll 1
  for (int half = 0; half < 2; half++) {
    int qt2 = half ? (7 - ip) : ip;
    int last = 2*qt2 + 1;

    const u16* qbase = Q + ((size_t)bh*SS + qt2*128 + w*16 + lq)*HD;
    bf16x8 qa0 = *(const bf16x8*)(qbase + g*8);
    bf16x8 qa1 = *(const bf16x8*)(qbase + g*8 + 32);

    f32x4 o[4];
    #pragma unroll
    for (int nb=0;nb<4;nb++) o[nb] = (f32x4){0.f,0.f,0.f,0.f};
    float mrun[4], lrun[4];
    #pragma unroll
    for (int r=0;r<4;r++) { mrun[r] = -1e30f; lrun[r] = 0.f; }

    #pragma unroll 1
    for (int kt = 0; kt <= last; kt++) {
      __syncthreads();   // prior iter's LDS reads complete
      *(bf16x8*)&Ks[kw] = kreg;
      *(bf16x8*)&Vs[kw] = vreg;
      __syncthreads();
      if (kt < last) {   // prefetch next tile
        kreg = *(const bf16x8*)(kgb + (size_t)(kt+1)*64*HD);
        vreg = *(const bf16x8*)(vgb + (kt+1)*64);
      } else if (half == 0) {  // prefetch tile 0 for the second q-tile
        kreg = *(const bf16x8*)kgb;
        vreg = *(const bf16x8*)vgb;
      }
      if (kt*64 > qt2*128 + w*16 + 15) continue;

      // ---- S = Q K^T ----
      f32x4 s[4];
      #pragma unroll
      for (int nb=0;nb<4;nb++) s[nb] = (f32x4){0.f,0.f,0.f,0.f};
      #pragma unroll
      for (int ks=0; ks<2; ks++) {
        bf16x8 aq = ks ? qa1 : qa0;
        #pragma unroll
        for (int nb=0;nb<4;nb++) {
          bf16x8 kb = *(const bf16x8*)&Ks[(lq + 16*nb)*64 + (((g + 4*ks) ^ l7) << 3)];
          s[nb] = __builtin_amdgcn_mfma_f32_16x16x32_bf16(aq, kb, s[nb], 0, 0, 0);
        }
      }

      // ---- mask + online softmax ----
      bool diag = (kt*64 + 63 > qt2*128 + w*16);   // wave-uniform
      #pragma unroll
      for (int r=0;r<4;r++) {
        int qrow = qt2*128 + w*16 + g*4 + r;
        if (diag) {
          #pragma unroll
          for (int nb=0;nb<4;nb++)
            if (kt*64 + lq + 16*nb > qrow) s[nb][r] = -1e30f;
        }
        float rm = fmaxf(fmaxf(s[0][r], s[1][r]), fmaxf(s[2][r], s[3][r]));
        #pragma unroll
        for (int off=1; off<16; off<<=1) rm = fmaxf(rm, __shfl_xor(rm, off));
        float mnew = fmaxf(mrun[r], rm);
        float corr = __expf(mrun[r] - mnew);
        float psum = 0.f;
        int mrow = g*4 + r;
        #pragma unroll
        for (int nb=0;nb<4;nb++) {
          float p = __expf(s[nb][r] - mnew);
          psum += p;
          Ps[pbase + mrow*64 + ((((lq>>3) + 2*nb) ^ (mrow&7)) << 3) + l7] = f2bf(p);
        }
        #pragma unroll
        for (int off=1; off<16; off<<=1) psum += __shfl_xor(psum, off);
        lrun[r] = lrun[r]*corr + psum;
        mrun[r] = mnew;
        #pragma unroll
        for (int nb=0;nb<4;nb++) o[nb][r] *= corr;
      }

      // ---- O += P V ----
      #pragma unroll
      for (int ks=0; ks<2; ks++) {
        bf16x8 pa = *(const bf16x8*)&Ps[pbase + lq*64 + (((g + 4*ks) ^ l7) << 3)];
        #pragma unroll
        for (int nb=0;nb<4;nb++) {
          bf16x8 vb = *(const bf16x8*)&Vs[(lq + 16*nb)*64 + (((g + 4*ks) ^ l7) << 3)];
          o[nb] = __builtin_amdgcn_mfma_f32_16x16x32_bf16(pa, vb, o[nb], 0, 0, 0);
        }
      }
    }

    // ---- epilogue for this half ----
    #pragma unroll
    for (int r=0;r<4;r++) {
      float inv = 1.f / lrun[r];
      int qrow = qt2*128 + w*16 + g*4 + r;
      u16* cp = ctxb + ((size_t)b*SS + qrow)*DM + h*HD;
      #pragma unroll
      for (int nb=0;nb<4;nb++) cp[lq + 16*nb] = f2bf(o[nb][r] * inv);
    }
  }
}

// ---------------- LayerNorm in-place on x, dual write (f32 + bf16) ----------------
__global__ __launch_bounds__(256) void k_ln(
    float* __restrict__ x, const float* __restrict__ g,
    const float* __restrict__ b, u16* __restrict__ xb) {
  int row = blockIdx.x*4 + (threadIdx.x>>6);
  int lane = threadIdx.x & 63;
  float* xr = x + (size_t)row*DM;
  float vals[8]; float s1=0.f, s2=0.f;
  #pragma unroll
  for (int u=0;u<8;u++){ float vv = xr[lane + 64*u]; vals[u]=vv; s1+=vv; s2+=vv*vv; }
  #pragma unroll
  for (int off=1; off<64; off<<=1){ s1 += __shfl_xor(s1,off); s2 += __shfl_xor(s2,off); }
  float mu  = s1 * (1.0f/DM);
  float var = s2 * (1.0f/DM) - mu*mu;
  float inv = rsqrtf(var + 1e-5f);
  u16* xbr = xb + (size_t)row*DM;
  #pragma unroll
  for (int u=0;u<8;u++){
    int c = lane+64*u;
    float vv = (vals[u]-mu)*inv*g[c] + b[c];
    xr[c] = vv;
    xbr[c] = f2bf(vv);
  }
}

// ---------------- head: out = 1.5*tanh(x@w^T + b) ----------------
__global__ __launch_bounds__(256) void k_head(
    const float* __restrict__ x, const float* __restrict__ w,
    const float* __restrict__ b, float* __restrict__ out) {
  int row = blockIdx.x*4 + (threadIdx.x>>6);
  int lane = threadIdx.x & 63;
  const float* xr = x + (size_t)row*DM;
  float acc = 0.f;
  #pragma unroll
  for (int u=0;u<8;u++) acc += xr[lane+64*u]*w[lane+64*u];
  #pragma unroll
  for (int off=1; off<64; off<<=1) acc += __shfl_xor(acc,off);
  if (lane == 0) out[row] = 1.5f * tanhf(acc + b[0]);
}

extern "C" void kernel_launch(void* const* d_in, const int* in_sizes, int n_in,
                              void* d_out, int out_size, void* d_ws, size_t ws_size,
                              hipStream_t stream) {
  (void)in_sizes; (void)n_in; (void)out_size; (void)ws_size;
  const float* feat      = (const float*)d_in[0];
  const float* hist_w    = (const float*)d_in[1];
  const float* hist_b    = (const float*)d_in[2];
  const float* query_w   = (const float*)d_in[3];
  const float* query_b   = (const float*)d_in[4];
  const float* in_proj_w = (const float*)d_in[5];
  const float* in_proj_b = (const float*)d_in[6];
  const float* attn_w    = (const float*)d_in[7];
  const float* attn_b    = (const float*)d_in[8];
  const float* ln_g      = (const float*)d_in[9];
  const float* ln_b      = (const float*)d_in[10];
  const float* out_w     = (const float*)d_in[11];
  const float* out_b     = (const float*)d_in[12];
  float* out = (float*)d_out;

  float* ws = (float*)d_ws;
  const size_t P = (size_t)NROWS * DM;   // 8.39M elems
  float* x    = ws;                      // fp32 residual stream
  u16* xb     = (u16*)(ws + P);          // bf16 x
  u16* histb  = xb + P;                  // bf16 history (both layers)
  u16* ctxb   = histb + P;               // bf16 attention context
  u16* qbf    = ctxb + P;                // bf16 Q (b,h,s,d) prescaled
  u16* kbf    = qbf + P;                 // bf16 K (b,h,s,d)
  u16* vtb    = kbf + P;                 // bf16 V^T (b,h,d,s)
  u16* wipb   = vtb + P;                 // bf16 in_proj_w (2*1536*512)
  u16* wob    = wipb + (size_t)2*3*DM*DM;// bf16 attn_out_w (2*512*512)

  {
    int n4i = 2*3*DM*DM/4, n4o = 2*DM*DM/4;
    k_f2bf_v<<<(n4i+255)/256, 256, 0, stream>>>(in_proj_w, wipb, n4i);
    k_f2bf_v<<<(n4o+255)/256, 256, 0, stream>>>(attn_w, wob, n4o);
  }
  k_input_proj<<<NROWS/16, 256, 0, stream>>>(feat, hist_w, hist_b, query_w, query_b, histb, x, xb);

  for (int l = 0; l < 2; l++) {
    const u16* wq  = wipb + (size_t)l*3*DM*DM;
    const u16* wkv = wq + (size_t)DM*DM;
    const float* bq  = in_proj_b + (size_t)l*3*DM;
    const float* bkv = bq + DM;
    k_bgemm_qkv<<<1536, 256, 0, stream>>>(xb, histb, wq, wkv, bq, bkv, qbf, kbf, vtb);
    dim3 ga(4, BB*NH);
    k_attn_mfma<<<ga, 512, 0, stream>>>(qbf, kbf, vtb, ctxb);
    const u16* wo = wob + (size_t)l*DM*DM;
    const float* bo = attn_b + (size_t)l*DM;
    k_bgemm_o<<<512, 256, 0, stream>>>(ctxb, wo, bo, x);
    k_ln<<<NROWS/4, 256, 0, stream>>>(x, ln_g + (size_t)l*DM, ln_b + (size_t)l*DM, xb);
  }
  k_head<<<NROWS/4, 256, 0, stream>>>(x, out_w, out_b, out);
}